// Round 1
// baseline (3179.247 us; speedup 1.0000x reference)
//
#include <hip/hip_runtime.h>
#include <math.h>

// Problem constants: B=2, L=2048, D=1024, H=16, hd=64, Dff=4096
#define SEQ_L 2048
#define DM    1024
#define NH    16
#define HD    64
#define BL    4096          // B*L
#define DFF   4096

// ---------------------------------------------------------------------------
// Block-wide sum reduce (256 threads, 4 waves)
// ---------------------------------------------------------------------------
__device__ __forceinline__ float block_sum(float v, float* red, int tid) {
#pragma unroll
    for (int m = 32; m; m >>= 1) v += __shfl_xor(v, m);
    if ((tid & 63) == 0) red[tid >> 6] = v;
    __syncthreads();
    v = red[0] + red[1] + red[2] + red[3];
    __syncthreads();   // allow red[] reuse
    return v;
}

__device__ __forceinline__ float gelu_erf(float x) {
    return 0.5f * x * (1.f + erff(x * 0.70710678118654752440f));
}

// ---------------------------------------------------------------------------
// LayerNorm over rows of 1024. grid = rows, block = 256
// ---------------------------------------------------------------------------
__global__ __launch_bounds__(256) void ln_kernel(const float* __restrict__ x,
                                                 const float* __restrict__ g,
                                                 const float* __restrict__ b,
                                                 float* __restrict__ out) {
    const int row = blockIdx.x;
    const int tid = threadIdx.x;
    __shared__ float red[4];
    const float4 xv = *(const float4*)(x + (size_t)row * DM + tid * 4);
    float s = xv.x + xv.y + xv.z + xv.w;
    s = block_sum(s, red, tid);
    const float mean = s * (1.f / (float)DM);
    float dx0 = xv.x - mean, dx1 = xv.y - mean, dx2 = xv.z - mean, dx3 = xv.w - mean;
    float ss = dx0 * dx0 + dx1 * dx1 + dx2 * dx2 + dx3 * dx3;
    ss = block_sum(ss, red, tid);
    const float var = ss * (1.f / (float)DM);
    const float rs = 1.f / sqrtf(var + 1e-5f);
    const float4 gv = *(const float4*)(g + tid * 4);
    const float4 bv = *(const float4*)(b + tid * 4);
    float4 o;
    o.x = dx0 * rs * gv.x + bv.x;
    o.y = dx1 * rs * gv.y + bv.y;
    o.z = dx2 * rs * gv.z + bv.z;
    o.w = dx3 * rs * gv.w + bv.w;
    *(float4*)(out + (size_t)row * DM + tid * 4) = o;
}

// ---------------------------------------------------------------------------
// Residual + Poincare projection: out = project(a + c), rows of 1024.
// In-place safe (all reads precede all writes via the reduce barrier).
// ---------------------------------------------------------------------------
__global__ __launch_bounds__(256) void resproj_kernel(const float* __restrict__ a,
                                                      const float* __restrict__ c,
                                                      float* __restrict__ out) {
    const int row = blockIdx.x;
    const int tid = threadIdx.x;
    __shared__ float red[4];
    const float4 av = *(const float4*)(a + (size_t)row * DM + tid * 4);
    const float4 cv = *(const float4*)(c + (size_t)row * DM + tid * 4);
    float4 sv;
    sv.x = av.x + cv.x; sv.y = av.y + cv.y; sv.z = av.z + cv.z; sv.w = av.w + cv.w;
    float ss = sv.x * sv.x + sv.y * sv.y + sv.z * sv.z + sv.w * sv.w;
    ss = block_sum(ss, red, tid);
    const float n = sqrtf(ss);
    const float mx = 1.f - 1e-5f;
    const float scale = (n > mx) ? (mx / fmaxf(n, 1e-12f)) : 1.f;
    sv.x *= scale; sv.y *= scale; sv.z *= scale; sv.w *= scale;
    *(float4*)(out + (size_t)row * DM + tid * 4) = sv;
}

// ---------------------------------------------------------------------------
// Per-head (64-dim) Poincare projection, one wave per vector.
// Optionally emits ||v||^2 after projection (for K).
// ---------------------------------------------------------------------------
__global__ __launch_bounds__(256) void headproj_kernel(float* __restrict__ p,
                                                       float* __restrict__ n2out,
                                                       int nvec) {
    const int vec = blockIdx.x * 4 + (threadIdx.x >> 6);
    const int lane = threadIdx.x & 63;
    if (vec >= nvec) return;
    float v = p[(size_t)vec * HD + lane];
    float s = v * v;
#pragma unroll
    for (int m = 32; m; m >>= 1) s += __shfl_xor(s, m);
    const float n = sqrtf(s);
    const float mx = 1.f - 1e-5f;
    const float scale = (n > mx) ? (mx / fmaxf(n, 1e-12f)) : 1.f;
    v *= scale;
    p[(size_t)vec * HD + lane] = v;
    if (n2out != nullptr && lane == 0) n2out[vec] = s * scale * scale;
}

// ---------------------------------------------------------------------------
// fp32 NT GEMM: C[M,N] = A[M,K] @ B[N,K]^T + bias[N]  (ACT==1: exact-erf GELU)
// 64x64 tile, BK=16, 256 threads, 4x4 microtile. M,N,K multiples of 64/16.
// ---------------------------------------------------------------------------
template <int ACT>
__global__ __launch_bounds__(256) void gemm_nt_kernel(const float* __restrict__ A,
                                                      const float* __restrict__ Bw,
                                                      const float* __restrict__ bias,
                                                      float* __restrict__ C,
                                                      int M, int N, int K) {
    __shared__ __align__(16) float As[16][68];
    __shared__ __align__(16) float Bs[16][68];
    const int tid = threadIdx.x;
    const int tx = tid & 15;       // output col group
    const int ty = tid >> 4;       // output row group
    const int n0 = blockIdx.x * 64;
    const int m0 = blockIdx.y * 64;
    const int lr = tid >> 2;          // 0..63: tile row for loading
    const int lk = (tid & 3) * 4;     // 0,4,8,12: k offset for loading
    const float* Ap = A + (size_t)(m0 + lr) * K + lk;
    const float* Bp = Bw + (size_t)(n0 + lr) * K + lk;

    float acc[4][4] = {};
    for (int kt = 0; kt < K; kt += 16) {
        const float4 av = *(const float4*)(Ap + kt);
        const float4 bv = *(const float4*)(Bp + kt);
        __syncthreads();
        As[lk + 0][lr] = av.x; As[lk + 1][lr] = av.y;
        As[lk + 2][lr] = av.z; As[lk + 3][lr] = av.w;
        Bs[lk + 0][lr] = bv.x; Bs[lk + 1][lr] = bv.y;
        Bs[lk + 2][lr] = bv.z; Bs[lk + 3][lr] = bv.w;
        __syncthreads();
#pragma unroll
        for (int kk = 0; kk < 16; ++kk) {
            const float4 a = *(const float4*)&As[kk][ty * 4];
            const float4 b = *(const float4*)&Bs[kk][tx * 4];
            acc[0][0] += a.x * b.x; acc[0][1] += a.x * b.y; acc[0][2] += a.x * b.z; acc[0][3] += a.x * b.w;
            acc[1][0] += a.y * b.x; acc[1][1] += a.y * b.y; acc[1][2] += a.y * b.z; acc[1][3] += a.y * b.w;
            acc[2][0] += a.z * b.x; acc[2][1] += a.z * b.y; acc[2][2] += a.z * b.z; acc[2][3] += a.z * b.w;
            acc[3][0] += a.w * b.x; acc[3][1] += a.w * b.y; acc[3][2] += a.w * b.z; acc[3][3] += a.w * b.w;
        }
    }
    const float4 bias4 = *(const float4*)(bias + n0 + tx * 4);
#pragma unroll
    for (int i = 0; i < 4; ++i) {
        float4 c;
        c.x = acc[i][0] + bias4.x;
        c.y = acc[i][1] + bias4.y;
        c.z = acc[i][2] + bias4.z;
        c.w = acc[i][3] + bias4.w;
        if (ACT == 1) {
            c.x = gelu_erf(c.x); c.y = gelu_erf(c.y);
            c.z = gelu_erf(c.z); c.w = gelu_erf(c.w);
        }
        *(float4*)(C + (size_t)(m0 + ty * 4 + i) * N + n0 + tx * 4) = c;
    }
}

// ---------------------------------------------------------------------------
// Flash-style hyperbolic attention.
// scores = (2*q.k - ||k||^2)/temp  (q^2 row-constant dropped; softmax-invariant)
// grid: x = q-tile (L/16), y = head, z = batch. block = 256 (=16 rows x 16).
// q,k,v layout: [B*L, H*hd] (head h occupies cols h*64..h*64+63).
// ---------------------------------------------------------------------------
__global__ __launch_bounds__(256) void attn_kernel(const float* __restrict__ q,
                                                   const float* __restrict__ k,
                                                   const float* __restrict__ v,
                                                   const float* __restrict__ k2v,
                                                   float* __restrict__ o) {
    const int qt = blockIdx.x, h = blockIdx.y, b = blockIdx.z;
    const int tid = threadIdx.x;
    const int ty = tid >> 4;   // q row in tile (0..15)
    const int tx = tid & 15;   // col group (0..15)
    __shared__ __align__(16) float Qs[16][68];
    __shared__ __align__(16) float Ks[64][68];
    __shared__ __align__(16) float Vs[64][68];
    __shared__ __align__(16) float Ss[16][68];
    __shared__ float K2s[64];

    const size_t base = ((size_t)b * SEQ_L) * DM + h * HD;
    *(float4*)&Qs[ty][tx * 4] =
        *(const float4*)(q + base + (size_t)(qt * 16 + ty) * DM + tx * 4);

    float m_i = -INFINITY, l_i = 0.f;
    float ax = 0.f, ay = 0.f, az = 0.f, aw = 0.f;

    for (int kt = 0; kt < SEQ_L / 64; ++kt) {
        __syncthreads();
#pragma unroll
        for (int i = 0; i < 4; ++i) {
            const int r = ty + 16 * i;
            const size_t gidx = base + (size_t)(kt * 64 + r) * DM + tx * 4;
            *(float4*)&Ks[r][tx * 4] = *(const float4*)(k + gidx);
            *(float4*)&Vs[r][tx * 4] = *(const float4*)(v + gidx);
            if (tx == 0) K2s[r] = k2v[(size_t)(b * SEQ_L + kt * 64 + r) * NH + h];
        }
        __syncthreads();

        // scores for the 4 keys j = tx*4 + jj
        float s0 = 0.f, s1 = 0.f, s2 = 0.f, s3 = 0.f;
        {
            const int j = tx * 4;
#pragma unroll
            for (int d4 = 0; d4 < 16; ++d4) {
                const float4 qv = *(const float4*)&Qs[ty][d4 * 4];
                const float4 k0 = *(const float4*)&Ks[j + 0][d4 * 4];
                const float4 k1 = *(const float4*)&Ks[j + 1][d4 * 4];
                const float4 k2 = *(const float4*)&Ks[j + 2][d4 * 4];
                const float4 k3 = *(const float4*)&Ks[j + 3][d4 * 4];
                s0 += qv.x * k0.x + qv.y * k0.y + qv.z * k0.z + qv.w * k0.w;
                s1 += qv.x * k1.x + qv.y * k1.y + qv.z * k1.z + qv.w * k1.w;
                s2 += qv.x * k2.x + qv.y * k2.y + qv.z * k2.z + qv.w * k2.w;
                s3 += qv.x * k3.x + qv.y * k3.y + qv.z * k3.z + qv.w * k3.w;
            }
            s0 = (2.f * s0 - K2s[j + 0]) * 0.125f;
            s1 = (2.f * s1 - K2s[j + 1]) * 0.125f;
            s2 = (2.f * s2 - K2s[j + 2]) * 0.125f;
            s3 = (2.f * s3 - K2s[j + 3]) * 0.125f;
        }

        // online softmax (row state replicated across the row's 16 lanes)
        float lmax = fmaxf(fmaxf(s0, s1), fmaxf(s2, s3));
#pragma unroll
        for (int m = 8; m; m >>= 1) lmax = fmaxf(lmax, __shfl_xor(lmax, m));
        const float m_new = fmaxf(m_i, lmax);
        const float alpha = __expf(m_i - m_new);
        const float p0 = __expf(s0 - m_new);
        const float p1 = __expf(s1 - m_new);
        const float p2 = __expf(s2 - m_new);
        const float p3 = __expf(s3 - m_new);
        float psum = p0 + p1 + p2 + p3;
#pragma unroll
        for (int m = 8; m; m >>= 1) psum += __shfl_xor(psum, m);
        l_i = l_i * alpha + psum;
        m_i = m_new;

        Ss[ty][tx * 4 + 0] = p0;
        Ss[ty][tx * 4 + 1] = p1;
        Ss[ty][tx * 4 + 2] = p2;
        Ss[ty][tx * 4 + 3] = p3;
        __syncthreads();

        ax *= alpha; ay *= alpha; az *= alpha; aw *= alpha;
#pragma unroll
        for (int j = 0; j < 64; ++j) {
            const float pj = Ss[ty][j];
            const float4 vv = *(const float4*)&Vs[j][tx * 4];
            ax += pj * vv.x; ay += pj * vv.y; az += pj * vv.z; aw += pj * vv.w;
        }
    }
    const float inv = 1.f / l_i;
    float4 res;
    res.x = ax * inv; res.y = ay * inv; res.z = az * inv; res.w = aw * inv;
    *(float4*)(o + base + (size_t)(qt * 16 + ty) * DM + tx * 4) = res;
}

// ---------------------------------------------------------------------------
// Launch
// ---------------------------------------------------------------------------
extern "C" void kernel_launch(void* const* d_in, const int* in_sizes, int n_in,
                              void* d_out, int out_size, void* d_ws, size_t ws_size,
                              hipStream_t stream) {
    const float* x   = (const float*)d_in[0];
    const float* wq  = (const float*)d_in[1];
    const float* bq  = (const float*)d_in[2];
    const float* wk  = (const float*)d_in[3];
    const float* bk  = (const float*)d_in[4];
    const float* wv  = (const float*)d_in[5];
    const float* bv  = (const float*)d_in[6];
    const float* wo  = (const float*)d_in[7];
    const float* bo  = (const float*)d_in[8];
    const float* g1  = (const float*)d_in[9];
    const float* b1  = (const float*)d_in[10];
    const float* g2  = (const float*)d_in[11];
    const float* b2  = (const float*)d_in[12];
    const float* w1  = (const float*)d_in[13];
    const float* bf1 = (const float*)d_in[14];
    const float* w2  = (const float*)d_in[15];
    const float* bf2 = (const float*)d_in[16];
    float* out = (float*)d_out;
    float* ws  = (float*)d_ws;

    const size_t SZ = (size_t)BL * DM;   // 4M floats per activation buffer
    float* xn  = ws;            // [0, 4M)
    float* qb  = ws + SZ;       // [4M, 8M)
    float* kb  = ws + 2 * SZ;   // [8M, 12M)
    float* vb  = ws + 3 * SZ;   // [12M, 16M)
    float* aO  = ws + 4 * SZ;   // [16M, 20M)
    float* k2  = ws + 5 * SZ;   // [20M, 20M+64K)
    float* P   = xn;            // reuse after QKV
    float* x1  = out;           // d_out doubles as x1
    float* xn2 = xn;            // reuse after P consumed
    float* hbuf = qb;           // [4M, 20M): 16M floats (q,k,v,aO dead)
    float* y2  = xn;            // reuse after xn2 consumed

    // 1. LN1
    ln_kernel<<<BL, 256, 0, stream>>>(x, g1, b1, xn);
    // 2. QKV projections
    gemm_nt_kernel<0><<<dim3(DM / 64, BL / 64), 256, 0, stream>>>(xn, wq, bq, qb, BL, DM, DM);
    gemm_nt_kernel<0><<<dim3(DM / 64, BL / 64), 256, 0, stream>>>(xn, wk, bk, kb, BL, DM, DM);
    gemm_nt_kernel<0><<<dim3(DM / 64, BL / 64), 256, 0, stream>>>(xn, wv, bv, vb, BL, DM, DM);
    // 3. Poincare projection on q, k heads (k also emits ||k||^2)
    const int nvec = BL * NH;
    headproj_kernel<<<nvec / 4, 256, 0, stream>>>(qb, nullptr, nvec);
    headproj_kernel<<<nvec / 4, 256, 0, stream>>>(kb, k2, nvec);
    // 4. Attention
    attn_kernel<<<dim3(SEQ_L / 16, NH, 2), 256, 0, stream>>>(qb, kb, vb, k2, aO);
    // 5. Output projection
    gemm_nt_kernel<0><<<dim3(DM / 64, BL / 64), 256, 0, stream>>>(aO, wo, bo, P, BL, DM, DM);
    // 6. x1 = project(x + P)   (into d_out)
    resproj_kernel<<<BL, 256, 0, stream>>>(x, P, x1);
    // 7. LN2
    ln_kernel<<<BL, 256, 0, stream>>>(x1, g2, b2, xn2);
    // 8. FFN1 + GELU
    gemm_nt_kernel<1><<<dim3(DFF / 64, BL / 64), 256, 0, stream>>>(xn2, w1, bf1, hbuf, BL, DFF, DM);
    // 9. FFN2
    gemm_nt_kernel<0><<<dim3(DM / 64, BL / 64), 256, 0, stream>>>(hbuf, w2, bf2, y2, BL, DM, DFF);
    // 10. out = project(x1 + y2)  (in-place on d_out)
    resproj_kernel<<<BL, 256, 0, stream>>>(x1, y2, out);
}

// Round 2
// 516.765 us; speedup vs baseline: 6.1522x; 6.1522x over previous
//
#include <hip/hip_runtime.h>
#include <math.h>

// Problem constants: B=2, L=2048, D=1024, H=16, hd=64, Dff=4096
#define SEQ_L 2048
#define DM    1024
#define NH    16
#define HD    64
#define BL    4096          // B*L
#define DFF   4096
#define QKV_S 3072          // fused qkv row stride

typedef __attribute__((ext_vector_type(8))) short short8;   // 8 bf16 (4 VGPRs)
typedef __attribute__((ext_vector_type(4))) short s16x4;    // 4 bf16
typedef __attribute__((ext_vector_type(4))) float f32x4;    // MFMA C/D frag

#define AS1 __attribute__((address_space(1)))
#define AS3 __attribute__((address_space(3)))

// async global->LDS, 16B per lane, lands at ldsbase + lane*16
__device__ __forceinline__ void gl_lds16(const void* g, void* l) {
    __builtin_amdgcn_global_load_lds((const AS1 void*)g, (AS3 void*)l, 16, 0, 0);
}

// fp32 -> bf16 round-to-nearest-even
__device__ __forceinline__ short f2bf(float x) {
    unsigned u = __float_as_uint(x);
    u += 0x7fff + ((u >> 16) & 1);
    return (short)(u >> 16);
}

__device__ __forceinline__ short8 pack8(float4 a, float4 b) {
    short8 r;
    r[0] = f2bf(a.x); r[1] = f2bf(a.y); r[2] = f2bf(a.z); r[3] = f2bf(a.w);
    r[4] = f2bf(b.x); r[5] = f2bf(b.y); r[6] = f2bf(b.z); r[7] = f2bf(b.w);
    return r;
}

__device__ __forceinline__ float gelu_erf(float x) {
    return 0.5f * x * (1.f + erff(x * 0.70710678118654752440f));
}

__device__ __forceinline__ float block_sum(float v, float* red, int tid) {
#pragma unroll
    for (int m = 32; m; m >>= 1) v += __shfl_xor(v, m);
    if ((tid & 63) == 0) red[tid >> 6] = v;
    __syncthreads();
    v = red[0] + red[1] + red[2] + red[3];
    __syncthreads();
    return v;
}

// ---------------------------------------------------------------------------
// Weight fp32 -> bf16 conversion: wq|wk|wv|wo|w1|w2 into one contiguous buffer
// (makes wq/wk/wv a contiguous [3072][1024] for the fused QKV GEMM).
// grid = 12288, block = 256, one float4 per thread.
// ---------------------------------------------------------------------------
__global__ __launch_bounds__(256) void cvt6_kernel(
    const float* __restrict__ wq, const float* __restrict__ wk,
    const float* __restrict__ wv, const float* __restrict__ wo,
    const float* __restrict__ w1, const float* __restrict__ w2,
    short* __restrict__ dst) {
    const size_t i = (size_t)blockIdx.x * 256 + threadIdx.x;  // float4 index
    const float* src;
    size_t off;
    if (i < 1048576) {            // wq,wk,wv,wo: 256K float4 each
        const int seg = (int)(i >> 18);
        off = i & 262143;
        src = seg == 0 ? wq : seg == 1 ? wk : seg == 2 ? wv : wo;
    } else if (i < 2097152) { src = w1; off = i - 1048576; }
    else                    { src = w2; off = i - 2097152; }
    const float4 v = ((const float4*)src)[off];
    const s16x4 o = {f2bf(v.x), f2bf(v.y), f2bf(v.z), f2bf(v.w)};
    ((s16x4*)dst)[i] = o;
}

// ---------------------------------------------------------------------------
// LayerNorm over rows of 1024, bf16 output (feeds MFMA GEMMs only).
// ---------------------------------------------------------------------------
__global__ __launch_bounds__(256) void ln_bf16_kernel(const float* __restrict__ x,
                                                      const float* __restrict__ g,
                                                      const float* __restrict__ b,
                                                      short* __restrict__ out) {
    const int row = blockIdx.x;
    const int tid = threadIdx.x;
    __shared__ float red[4];
    const float4 xv = *(const float4*)(x + (size_t)row * DM + tid * 4);
    float s = xv.x + xv.y + xv.z + xv.w;
    s = block_sum(s, red, tid);
    const float mean = s * (1.f / (float)DM);
    float dx0 = xv.x - mean, dx1 = xv.y - mean, dx2 = xv.z - mean, dx3 = xv.w - mean;
    float ss = dx0 * dx0 + dx1 * dx1 + dx2 * dx2 + dx3 * dx3;
    ss = block_sum(ss, red, tid);
    const float rs = 1.f / sqrtf(ss * (1.f / (float)DM) + 1e-5f);
    const float4 gv = *(const float4*)(g + tid * 4);
    const float4 bv = *(const float4*)(b + tid * 4);
    const s16x4 ob = {f2bf(dx0 * rs * gv.x + bv.x), f2bf(dx1 * rs * gv.y + bv.y),
                      f2bf(dx2 * rs * gv.z + bv.z), f2bf(dx3 * rs * gv.w + bv.w)};
    *(s16x4*)(out + (size_t)row * DM + tid * 4) = ob;
}

// ---------------------------------------------------------------------------
// Residual + Poincare projection (fp32, in-place safe)
// ---------------------------------------------------------------------------
__global__ __launch_bounds__(256) void resproj_kernel(const float* __restrict__ a,
                                                      const float* __restrict__ c,
                                                      float* __restrict__ out) {
    const int row = blockIdx.x;
    const int tid = threadIdx.x;
    __shared__ float red[4];
    const float4 av = *(const float4*)(a + (size_t)row * DM + tid * 4);
    const float4 cv = *(const float4*)(c + (size_t)row * DM + tid * 4);
    float4 sv;
    sv.x = av.x + cv.x; sv.y = av.y + cv.y; sv.z = av.z + cv.z; sv.w = av.w + cv.w;
    float ss = sv.x * sv.x + sv.y * sv.y + sv.z * sv.z + sv.w * sv.w;
    ss = block_sum(ss, red, tid);
    const float n = sqrtf(ss);
    const float mx = 1.f - 1e-5f;
    const float scale = (n > mx) ? (mx / fmaxf(n, 1e-12f)) : 1.f;
    sv.x *= scale; sv.y *= scale; sv.z *= scale; sv.w *= scale;
    *(float4*)(out + (size_t)row * DM + tid * 4) = sv;
}

// ---------------------------------------------------------------------------
// Per-head (64-dim) Poincare projection on fused qkv ([BL][3072], fp32),
// one wave per vector; optionally emits ||v||^2 (post-projection).
// ---------------------------------------------------------------------------
__global__ __launch_bounds__(256) void headproj_kernel(float* __restrict__ p,
                                                       float* __restrict__ n2out) {
    const int vec = blockIdx.x * 4 + (threadIdx.x >> 6);
    const int lane = threadIdx.x & 63;
    const int row = vec >> 4, h = vec & 15;
    float* a = p + (size_t)row * QKV_S + h * HD + lane;
    const float v = *a;
    float s = v * v;
#pragma unroll
    for (int m = 32; m; m >>= 1) s += __shfl_xor(s, m);
    const float n = sqrtf(s);
    const float mx = 1.f - 1e-5f;
    const float scale = (n > mx) ? (mx / fmaxf(n, 1e-12f)) : 1.f;
    *a = v * scale;
    if (n2out != nullptr && lane == 0) n2out[vec] = s * scale * scale;
}

// ---------------------------------------------------------------------------
// bf16 MFMA NT GEMM (m97 pattern): C[M,N] = A[M,K] @ B[N,K]^T + bias
// Block 256 (4 waves), tile BM x 128, BK=32, 16x16x32 bf16 MFMA.
// BM=128: wave=64x64 (acc 4x4); BM=64: wave=32x64 (acc 2x4).
// FUSED: bias segmented per 1024 output cols (QKV). OUTBF: bf16 C. ACT: GELU.
// ---------------------------------------------------------------------------
template <int BM, int ACT, int OUTBF, int FUSED>
__global__ __launch_bounds__(256) void gemm_mfma(
    const short* __restrict__ A, const short* __restrict__ Bw,
    const float* __restrict__ bb0, const float* __restrict__ bb1,
    const float* __restrict__ bb2, void* __restrict__ Cout,
    int M, int N, int K) {
    constexpr int RT = BM / 32;
    __shared__ __align__(16) short As[BM * 32];
    __shared__ __align__(16) short Bs[128 * 32];
    const int tid = threadIdx.x;
    const int wv = tid >> 6, lane = tid & 63;
    const int m0 = blockIdx.y * BM, n0 = blockIdx.x * 128;
    const int wr = (wv & 1) * (BM / 2);
    const int wc = (wv >> 1) * 64;

    // staging: lane i -> row (i>>2), 16B chunk (i&3); dest = base + lane*16
    const int arow = wv * (BM / 4) + (lane >> 2);
    const int brow = wv * 32 + (lane >> 2);
    const short* Ag = A + (size_t)(m0 + arow) * K + (lane & 3) * 8;
    const short* Bg = Bw + (size_t)(n0 + brow) * K + (lane & 3) * 8;
    short* AsW = As + (wv * (BM / 4)) * 32;
    short* BsW = Bs + (wv * 32) * 32;

    const f32x4 z4 = {0.f, 0.f, 0.f, 0.f};
    f32x4 acc[RT][4];
#pragma unroll
    for (int r = 0; r < RT; ++r)
#pragma unroll
        for (int c = 0; c < 4; ++c) acc[r][c] = z4;

    const int lrow = lane & 15, kq = (lane >> 4) * 8;

    for (int kt = 0; kt < K; kt += 32) {
        __syncthreads();
        gl_lds16(Ag + kt, AsW);
        if constexpr (BM == 128) gl_lds16(Ag + (size_t)16 * K + kt, AsW + 16 * 32);
        gl_lds16(Bg + kt, BsW);
        gl_lds16(Bg + (size_t)16 * K + kt, BsW + 16 * 32);
        __syncthreads();
        short8 af[RT], bf[4];
#pragma unroll
        for (int r = 0; r < RT; ++r)
            af[r] = *(const short8*)&As[(wr + r * 16 + lrow) * 32 + kq];
#pragma unroll
        for (int c = 0; c < 4; ++c)
            bf[c] = *(const short8*)&Bs[(wc + c * 16 + lrow) * 32 + kq];
#pragma unroll
        for (int r = 0; r < RT; ++r)
#pragma unroll
            for (int c = 0; c < 4; ++c)
                acc[r][c] = __builtin_amdgcn_mfma_f32_16x16x32_bf16(af[r], bf[c], acc[r][c], 0, 0, 0);
    }

    // epilogue: C/D layout col = lane&15, row = (lane>>4)*4 + reg
    const int col = lane & 15, rb = (lane >> 4) * 4;
#pragma unroll
    for (int c = 0; c < 4; ++c) {
        const int gn = n0 + wc + c * 16 + col;
        float bias;
        if constexpr (FUSED) {
            const int seg = gn >> 10;
            bias = (seg == 0 ? bb0 : seg == 1 ? bb1 : bb2)[gn & 1023];
        } else {
            bias = bb0[gn];
        }
#pragma unroll
        for (int r = 0; r < RT; ++r) {
            const int gm = m0 + wr + r * 16 + rb;
#pragma unroll
            for (int i = 0; i < 4; ++i) {
                float v = acc[r][c][i] + bias;
                if constexpr (ACT) v = gelu_erf(v);
                if constexpr (OUTBF)
                    ((short*)Cout)[(size_t)(gm + i) * N + gn] = f2bf(v);
                else
                    ((float*)Cout)[(size_t)(gm + i) * N + gn] = v;
            }
        }
    }
}

// ---------------------------------------------------------------------------
// MFMA flash attention. scores = (2 q.k - ||k||^2)/8 (q^2 dropped, softmax-inv).
// Block 256 = 4 waves; 32 q-rows/wave (128/block). 64-key tiles in LDS (bf16).
// grid (L/128, H, B) = (16,16,2). qkv fp32 fused [BL][3072]; out aO bf16 [BL][1024].
// ---------------------------------------------------------------------------
__global__ __launch_bounds__(256) void attn_mfma(const float* __restrict__ qkv,
                                                 const float* __restrict__ k2v,
                                                 short* __restrict__ aO) {
    const int qt = blockIdx.x, h = blockIdx.y, b = blockIdx.z;
    const int tid = threadIdx.x, wv = tid >> 6, lane = tid & 63;
    __shared__ __align__(16) short Ks[64 * 72];      // [key][hd], +8 pad
    __shared__ __align__(16) short Vt[64 * 72];      // [hd][key], +8 pad
    __shared__ __align__(16) short Pb[4][32 * 72];   // per-wave P, [q][key], +8 pad
    __shared__ float K2s[64];

    const size_t rowbase = (size_t)b * SEQ_L;
    const float* qp = qkv + h * HD;
    const float* kp = qkv + DM + h * HD;
    const float* vp = qkv + 2 * DM + h * HD;

    const int lrow = lane & 15, kq8 = (lane >> 4) * 8;

    // Q A-frags in registers: A[m=lane&15][k=(lane>>4)*8+j], rt in {0,1}, kc in {0,1}
    short8 qf[2][2];
#pragma unroll
    for (int rt = 0; rt < 2; ++rt)
#pragma unroll
        for (int kc = 0; kc < 2; ++kc) {
            const float* s = qp + (rowbase + qt * 128 + wv * 32 + rt * 16 + lrow) * QKV_S
                             + kc * 32 + kq8;
            qf[rt][kc] = pack8(*(const float4*)s, *(const float4*)(s + 4));
        }

    const f32x4 z4 = {0.f, 0.f, 0.f, 0.f};
    f32x4 o[2][4], m_i[2], l_i[2];
#pragma unroll
    for (int rt = 0; rt < 2; ++rt) {
        m_i[rt] = (f32x4){-INFINITY, -INFINITY, -INFINITY, -INFINITY};
        l_i[rt] = z4;
#pragma unroll
        for (int ht = 0; ht < 4; ++ht) o[rt][ht] = z4;
    }

    const int skey = tid >> 2, schunk = (tid & 3) * 16;       // K staging
    const int vkey0 = (tid & 15) * 4, vhd0 = (tid >> 4) * 4;  // V transpose staging

    for (int kt = 0; kt < SEQ_L / 64; ++kt) {
        const int k0g = kt * 64;
        __syncthreads();
        {   // K tile: [key][hd] bf16
            const float* s = kp + (rowbase + k0g + skey) * QKV_S + schunk;
            const float4 a0 = *(const float4*)(s);
            const float4 a1 = *(const float4*)(s + 4);
            const float4 a2 = *(const float4*)(s + 8);
            const float4 a3 = *(const float4*)(s + 12);
            *(short8*)&Ks[skey * 72 + schunk] = pack8(a0, a1);
            *(short8*)&Ks[skey * 72 + schunk + 8] = pack8(a2, a3);
        }
        {   // V tile transposed: Vt[hd][key] via 4x4 register transpose
            const float4 r0 = *(const float4*)(vp + (rowbase + k0g + vkey0 + 0) * QKV_S + vhd0);
            const float4 r1 = *(const float4*)(vp + (rowbase + k0g + vkey0 + 1) * QKV_S + vhd0);
            const float4 r2 = *(const float4*)(vp + (rowbase + k0g + vkey0 + 2) * QKV_S + vhd0);
            const float4 r3 = *(const float4*)(vp + (rowbase + k0g + vkey0 + 3) * QKV_S + vhd0);
            const s16x4 w0 = {f2bf(r0.x), f2bf(r1.x), f2bf(r2.x), f2bf(r3.x)};
            const s16x4 w1 = {f2bf(r0.y), f2bf(r1.y), f2bf(r2.y), f2bf(r3.y)};
            const s16x4 w2 = {f2bf(r0.z), f2bf(r1.z), f2bf(r2.z), f2bf(r3.z)};
            const s16x4 w3 = {f2bf(r0.w), f2bf(r1.w), f2bf(r2.w), f2bf(r3.w)};
            *(s16x4*)&Vt[(vhd0 + 0) * 72 + vkey0] = w0;
            *(s16x4*)&Vt[(vhd0 + 1) * 72 + vkey0] = w1;
            *(s16x4*)&Vt[(vhd0 + 2) * 72 + vkey0] = w2;
            *(s16x4*)&Vt[(vhd0 + 3) * 72 + vkey0] = w3;
        }
        if (tid < 64) K2s[tid] = k2v[(rowbase + k0g + tid) * NH + h];
        __syncthreads();

        // QK^T: S[2rt][4ct] 16x16 tiles
        f32x4 s[2][4];
#pragma unroll
        for (int ct = 0; ct < 4; ++ct) {
            const short8 kf0 = *(const short8*)&Ks[(ct * 16 + lrow) * 72 + kq8];
            const short8 kf1 = *(const short8*)&Ks[(ct * 16 + lrow) * 72 + 32 + kq8];
#pragma unroll
            for (int rt = 0; rt < 2; ++rt) {
                f32x4 t = z4;
                t = __builtin_amdgcn_mfma_f32_16x16x32_bf16(qf[rt][0], kf0, t, 0, 0, 0);
                t = __builtin_amdgcn_mfma_f32_16x16x32_bf16(qf[rt][1], kf1, t, 0, 0, 0);
                s[rt][ct] = t;
            }
        }
#pragma unroll
        for (int ct = 0; ct < 4; ++ct) {
            const float kk = K2s[ct * 16 + lrow] * 0.125f;   // col = lane&15
#pragma unroll
            for (int rt = 0; rt < 2; ++rt) s[rt][ct] = s[rt][ct] * 0.25f - kk;
        }

        // online softmax; lane owns rows (lane>>4)*4+reg, replicated over 16 cols
#pragma unroll
        for (int rt = 0; rt < 2; ++rt) {
            f32x4 mx;
#pragma unroll
            for (int i = 0; i < 4; ++i)
                mx[i] = fmaxf(fmaxf(s[rt][0][i], s[rt][1][i]), fmaxf(s[rt][2][i], s[rt][3][i]));
#pragma unroll
            for (int d = 8; d; d >>= 1)
#pragma unroll
                for (int i = 0; i < 4; ++i) mx[i] = fmaxf(mx[i], __shfl_xor(mx[i], d));
            f32x4 mn, al;
#pragma unroll
            for (int i = 0; i < 4; ++i) {
                mn[i] = fmaxf(m_i[rt][i], mx[i]);
                al[i] = __expf(m_i[rt][i] - mn[i]);
            }
            m_i[rt] = mn;
            f32x4 ps = z4;
#pragma unroll
            for (int ct = 0; ct < 4; ++ct) {
#pragma unroll
                for (int i = 0; i < 4; ++i) s[rt][ct][i] = __expf(s[rt][ct][i] - mn[i]);
                ps += s[rt][ct];
            }
#pragma unroll
            for (int d = 8; d; d >>= 1)
#pragma unroll
                for (int i = 0; i < 4; ++i) ps[i] += __shfl_xor(ps[i], d);
            l_i[rt] = l_i[rt] * al + ps;
#pragma unroll
            for (int ht = 0; ht < 4; ++ht) o[rt][ht] *= al;
            // P -> LDS (C layout -> A layout round-trip), bf16
#pragma unroll
            for (int ct = 0; ct < 4; ++ct)
#pragma unroll
                for (int i = 0; i < 4; ++i)
                    Pb[wv][(rt * 16 + (lane >> 4) * 4 + i) * 72 + ct * 16 + lrow] =
                        f2bf(s[rt][ct][i]);
        }

        // PV: O[2rt][4ht] += P(16x64) @ V(64keys x 64hd)
        short8 pf[2][2];
#pragma unroll
        for (int rt = 0; rt < 2; ++rt)
#pragma unroll
            for (int kc = 0; kc < 2; ++kc)
                pf[rt][kc] = *(const short8*)&Pb[wv][(rt * 16 + lrow) * 72 + kc * 32 + kq8];
#pragma unroll
        for (int ht = 0; ht < 4; ++ht) {
            const short8 vf0 = *(const short8*)&Vt[(ht * 16 + lrow) * 72 + kq8];
            const short8 vf1 = *(const short8*)&Vt[(ht * 16 + lrow) * 72 + 32 + kq8];
#pragma unroll
            for (int rt = 0; rt < 2; ++rt) {
                o[rt][ht] = __builtin_amdgcn_mfma_f32_16x16x32_bf16(pf[rt][0], vf0, o[rt][ht], 0, 0, 0);
                o[rt][ht] = __builtin_amdgcn_mfma_f32_16x16x32_bf16(pf[rt][1], vf1, o[rt][ht], 0, 0, 0);
            }
        }
    }

    // epilogue: normalize and store bf16
#pragma unroll
    for (int rt = 0; rt < 2; ++rt) {
        f32x4 inv;
#pragma unroll
        for (int i = 0; i < 4; ++i) inv[i] = 1.f / l_i[rt][i];
#pragma unroll
        for (int ht = 0; ht < 4; ++ht)
#pragma unroll
            for (int i = 0; i < 4; ++i)
                aO[(rowbase + qt * 128 + wv * 32 + rt * 16 + (lane >> 4) * 4 + i) * DM
                   + h * HD + ht * 16 + lrow] = f2bf(o[rt][ht][i] * inv[i]);
    }
}

// ---------------------------------------------------------------------------
// Launch
// ---------------------------------------------------------------------------
extern "C" void kernel_launch(void* const* d_in, const int* in_sizes, int n_in,
                              void* d_out, int out_size, void* d_ws, size_t ws_size,
                              hipStream_t stream) {
    const float* x   = (const float*)d_in[0];
    const float* wq  = (const float*)d_in[1];
    const float* bq  = (const float*)d_in[2];
    const float* wk  = (const float*)d_in[3];
    const float* bk  = (const float*)d_in[4];
    const float* wv  = (const float*)d_in[5];
    const float* bv  = (const float*)d_in[6];
    const float* wo  = (const float*)d_in[7];
    const float* bo  = (const float*)d_in[8];
    const float* g1  = (const float*)d_in[9];
    const float* b1  = (const float*)d_in[10];
    const float* g2  = (const float*)d_in[11];
    const float* b2  = (const float*)d_in[12];
    const float* w1  = (const float*)d_in[13];
    const float* bf1 = (const float*)d_in[14];
    const float* w2  = (const float*)d_in[15];
    const float* bf2 = (const float*)d_in[16];
    float* out = (float*)d_out;

    // ws layout (bytes), peak 80.25 MB (same footprint as round 1):
    char* base = (char*)d_ws;
    short* wbf  = (short*)base;                        // [0,24MB): bf16 wq|wk|wv|wo|w1|w2
    float* qkvF = (float*)(base + (24u << 20));        // [24,72MB): fused qkv fp32 [BL][3072]
    short* hbuf = (short*)(base + (40u << 20));        // [40,72MB): FFN hidden bf16 (qkv dead)
    short* xnb  = (short*)(base + (72u << 20));        // [72,80MB): LN out bf16 / aO / xn2b
    float* k2   = (float*)(base + (80u << 20));        // [80,80.25MB): ||k||^2 [BL][16]
    short* aO   = xnb;                                 // reuse (xnb dead after QKV)
    short* xn2b = xnb;                                 // reuse (aO dead after O-proj)
    float* P    = qkvF;                                // reuse (qkv dead after attn)
    float* y2   = qkvF;                                // reuse (P dead after resproj1)

    // 0. weights -> bf16 (contiguous, enables fused QKV)
    cvt6_kernel<<<12288, 256, 0, stream>>>(wq, wk, wv, wo, w1, w2, wbf);
    // 1. LN1 -> bf16
    ln_bf16_kernel<<<BL, 256, 0, stream>>>(x, g1, b1, xnb);
    // 2. fused QKV projection: [4096,1024] x [3072,1024]^T -> fp32 [4096][3072]
    gemm_mfma<128, 0, 0, 1><<<dim3(24, 32), 256, 0, stream>>>(
        xnb, wbf, bq, bk, bv, qkvF, BL, QKV_S, DM);
    // 3. Poincare per-head projection on q and k (k also emits ||k||^2)
    headproj_kernel<<<16384, 256, 0, stream>>>(qkvF, nullptr);
    headproj_kernel<<<16384, 256, 0, stream>>>(qkvF + DM, k2);
    // 4. flash MFMA attention -> aO bf16
    attn_mfma<<<dim3(16, 16, 2), 256, 0, stream>>>(qkvF, k2, aO);
    // 5. output projection -> P fp32
    gemm_mfma<64, 0, 0, 0><<<dim3(8, 64), 256, 0, stream>>>(
        aO, wbf + 3145728, bo, bo, bo, P, BL, DM, DM);
    // 6. x1 = project(x + P) -> d_out
    resproj_kernel<<<BL, 256, 0, stream>>>(x, P, out);
    // 7. LN2 -> bf16
    ln_bf16_kernel<<<BL, 256, 0, stream>>>(out, g2, b2, xn2b);
    // 8. FFN1 + GELU -> bf16 hidden
    gemm_mfma<128, 1, 1, 0><<<dim3(32, 32), 256, 0, stream>>>(
        xn2b, wbf + 4194304, bf1, bf1, bf1, hbuf, BL, DFF, DM);
    // 9. FFN2 -> fp32
    gemm_mfma<64, 0, 0, 0><<<dim3(8, 64), 256, 0, stream>>>(
        hbuf, wbf + 8388608, bf2, bf2, bf2, y2, BL, DM, DFF);
    // 10. out = project(x1 + y2)
    resproj_kernel<<<BL, 256, 0, stream>>>(out, y2, out);
}

// Round 3
// 438.185 us; speedup vs baseline: 7.2555x; 1.1793x over previous
//
#include <hip/hip_runtime.h>
#include <math.h>

// Problem constants: B=2, L=2048, D=1024, H=16, hd=64, Dff=4096
#define SEQ_L 2048
#define DM    1024
#define NH    16
#define HD    64
#define BL    4096          // B*L
#define DFF   4096
#define QKV_S 3072          // fused qkv row stride

typedef __attribute__((ext_vector_type(8))) short short8;   // 8 bf16 (4 VGPRs)
typedef __attribute__((ext_vector_type(4))) short s16x4;    // 4 bf16
typedef __attribute__((ext_vector_type(4))) float f32x4;    // MFMA C/D frag

#define AS1 __attribute__((address_space(1)))
#define AS3 __attribute__((address_space(3)))

// async global->LDS, 16B per lane, lands at ldsbase + lane*16
__device__ __forceinline__ void gl_lds16(const void* g, void* l) {
    __builtin_amdgcn_global_load_lds((const AS1 void*)g, (AS3 void*)l, 16, 0, 0);
}

// fp32 -> bf16 round-to-nearest-even
__device__ __forceinline__ short f2bf(float x) {
    unsigned u = __float_as_uint(x);
    u += 0x7fff + ((u >> 16) & 1);
    return (short)(u >> 16);
}
__device__ __forceinline__ float bf2f(short s) {
    return __uint_as_float(((unsigned)(unsigned short)s) << 16);
}

__device__ __forceinline__ float gelu_erf(float x) {
    return 0.5f * x * (1.f + erff(x * 0.70710678118654752440f));
}

__device__ __forceinline__ float block_sum(float v, float* red, int tid) {
#pragma unroll
    for (int m = 32; m; m >>= 1) v += __shfl_xor(v, m);
    if ((tid & 63) == 0) red[tid >> 6] = v;
    __syncthreads();
    v = red[0] + red[1] + red[2] + red[3];
    __syncthreads();
    return v;
}

// ---------------------------------------------------------------------------
// Weight fp32 -> bf16: wq|wk|wv|wo|w1|w2 contiguous (fused QKV needs this).
// ---------------------------------------------------------------------------
__global__ __launch_bounds__(256) void cvt6_kernel(
    const float* __restrict__ wq, const float* __restrict__ wk,
    const float* __restrict__ wv, const float* __restrict__ wo,
    const float* __restrict__ w1, const float* __restrict__ w2,
    short* __restrict__ dst) {
    const size_t i = (size_t)blockIdx.x * 256 + threadIdx.x;  // float4 index
    const float* src;
    size_t off;
    if (i < 1048576) {
        const int seg = (int)(i >> 18);
        off = i & 262143;
        src = seg == 0 ? wq : seg == 1 ? wk : seg == 2 ? wv : wo;
    } else if (i < 2097152) { src = w1; off = i - 1048576; }
    else                    { src = w2; off = i - 2097152; }
    const float4 v = ((const float4*)src)[off];
    const s16x4 o = {f2bf(v.x), f2bf(v.y), f2bf(v.z), f2bf(v.w)};
    ((s16x4*)dst)[i] = o;
}

// ---------------------------------------------------------------------------
// LayerNorm over rows of 1024, bf16 output.
// ---------------------------------------------------------------------------
__global__ __launch_bounds__(256) void ln_bf16_kernel(const float* __restrict__ x,
                                                      const float* __restrict__ g,
                                                      const float* __restrict__ b,
                                                      short* __restrict__ out) {
    const int row = blockIdx.x;
    const int tid = threadIdx.x;
    __shared__ float red[4];
    const float4 xv = *(const float4*)(x + (size_t)row * DM + tid * 4);
    float s = xv.x + xv.y + xv.z + xv.w;
    s = block_sum(s, red, tid);
    const float mean = s * (1.f / (float)DM);
    float dx0 = xv.x - mean, dx1 = xv.y - mean, dx2 = xv.z - mean, dx3 = xv.w - mean;
    float ss = dx0 * dx0 + dx1 * dx1 + dx2 * dx2 + dx3 * dx3;
    ss = block_sum(ss, red, tid);
    const float rs = 1.f / sqrtf(ss * (1.f / (float)DM) + 1e-5f);
    const float4 gv = *(const float4*)(g + tid * 4);
    const float4 bv = *(const float4*)(b + tid * 4);
    const s16x4 ob = {f2bf(dx0 * rs * gv.x + bv.x), f2bf(dx1 * rs * gv.y + bv.y),
                      f2bf(dx2 * rs * gv.z + bv.z), f2bf(dx3 * rs * gv.w + bv.w)};
    *(s16x4*)(out + (size_t)row * DM + tid * 4) = ob;
}

// ---------------------------------------------------------------------------
// Residual + Poincare projection (fp32, in-place safe)
// ---------------------------------------------------------------------------
__global__ __launch_bounds__(256) void resproj_kernel(const float* __restrict__ a,
                                                      const float* __restrict__ c,
                                                      float* __restrict__ out) {
    const int row = blockIdx.x;
    const int tid = threadIdx.x;
    __shared__ float red[4];
    const float4 av = *(const float4*)(a + (size_t)row * DM + tid * 4);
    const float4 cv = *(const float4*)(c + (size_t)row * DM + tid * 4);
    float4 sv;
    sv.x = av.x + cv.x; sv.y = av.y + cv.y; sv.z = av.z + cv.z; sv.w = av.w + cv.w;
    float ss = sv.x * sv.x + sv.y * sv.y + sv.z * sv.z + sv.w * sv.w;
    ss = block_sum(ss, red, tid);
    const float n = sqrtf(ss);
    const float mx = 1.f - 1e-5f;
    const float scale = (n > mx) ? (mx / fmaxf(n, 1e-12f)) : 1.f;
    sv.x *= scale; sv.y *= scale; sv.z *= scale; sv.w *= scale;
    *(float4*)(out + (size_t)row * DM + tid * 4) = sv;
}

// ---------------------------------------------------------------------------
// q/k prep: per-head Poincare projection + attention-layout bf16 buffers.
// One wave per (row, head): Qb/Kb [b][h][L][64] bf16, k2 [b][h][L] = ||k||^2/8.
// ---------------------------------------------------------------------------
__global__ __launch_bounds__(256) void qk_prep(const short* __restrict__ qkvB,
                                               short* __restrict__ Qb,
                                               short* __restrict__ Kb,
                                               float* __restrict__ k2) {
    const int tid = threadIdx.x, lane = tid & 63;
    const int vec = blockIdx.x * 4 + (tid >> 6);
    const int row = vec >> 4, h = vec & 15;
    const int b = row >> 11, l = row & 2047;
    const size_t dstv = ((size_t)(b * NH + h) * SEQ_L + l) * HD + lane;
    const float mx = 1.f - 1e-5f;
    {   // q
        const float v = bf2f(qkvB[(size_t)row * QKV_S + h * HD + lane]);
        float s = v * v;
#pragma unroll
        for (int m = 32; m; m >>= 1) s += __shfl_xor(s, m);
        const float n = sqrtf(s);
        const float sc = (n > mx) ? (mx / fmaxf(n, 1e-12f)) : 1.f;
        Qb[dstv] = f2bf(v * sc);
    }
    {   // k (+ prescaled squared norm)
        const float v = bf2f(qkvB[(size_t)row * QKV_S + DM + h * HD + lane]);
        float s = v * v;
#pragma unroll
        for (int m = 32; m; m >>= 1) s += __shfl_xor(s, m);
        const float n = sqrtf(s);
        const float sc = (n > mx) ? (mx / fmaxf(n, 1e-12f)) : 1.f;
        Kb[dstv] = f2bf(v * sc);
        if (lane == 0) k2[(size_t)(b * NH + h) * SEQ_L + l] = s * sc * sc * 0.125f;
    }
}

// ---------------------------------------------------------------------------
// v prep: transpose to Vtb [b][h][64 hd][L] bf16 via LDS tile.
// grid = 2*16*32 blocks, one 64-key x 64-hd tile each.
// ---------------------------------------------------------------------------
__global__ __launch_bounds__(256) void v_prep(const short* __restrict__ qkvB,
                                              short* __restrict__ Vtb) {
    const int blk = blockIdx.x;
    const int bh = blk >> 5, kt = blk & 31;
    const int b = bh >> 4, h = bh & 15;
    __shared__ short T[64 * 72];
    const int tid = threadIdx.x;
    {
        const int key = tid >> 2, ch = (tid & 3) * 16;
        const size_t src = ((size_t)b * SEQ_L + kt * 64 + key) * QKV_S + 2 * DM + h * HD + ch;
        *(short8*)&T[key * 72 + ch]     = *(const short8*)(qkvB + src);
        *(short8*)&T[key * 72 + ch + 8] = *(const short8*)(qkvB + src + 8);
    }
    __syncthreads();
    const int hd = tid >> 2, kc = (tid & 3) * 16;
    short8 o0, o1;
#pragma unroll
    for (int j = 0; j < 8; ++j) {
        o0[j] = T[(kc + j) * 72 + hd];
        o1[j] = T[(kc + 8 + j) * 72 + hd];
    }
    short* dst = Vtb + ((size_t)bh * HD + hd) * SEQ_L + kt * 64 + kc;
    *(short8*)dst = o0;
    *(short8*)(dst + 8) = o1;
}

// ---------------------------------------------------------------------------
// bf16 MFMA NT GEMM (m97 pattern): C[M,N] = A[M,K] @ B[N,K]^T + bias
// ---------------------------------------------------------------------------
template <int BM, int ACT, int OUTBF, int FUSED>
__global__ __launch_bounds__(256) void gemm_mfma(
    const short* __restrict__ A, const short* __restrict__ Bw,
    const float* __restrict__ bb0, const float* __restrict__ bb1,
    const float* __restrict__ bb2, void* __restrict__ Cout,
    int M, int N, int K) {
    constexpr int RT = BM / 32;
    __shared__ __align__(16) short As[BM * 32];
    __shared__ __align__(16) short Bs[128 * 32];
    const int tid = threadIdx.x;
    const int wv = tid >> 6, lane = tid & 63;
    const int m0 = blockIdx.y * BM, n0 = blockIdx.x * 128;
    const int wr = (wv & 1) * (BM / 2);
    const int wc = (wv >> 1) * 64;

    const int arow = wv * (BM / 4) + (lane >> 2);
    const int brow = wv * 32 + (lane >> 2);
    const short* Ag = A + (size_t)(m0 + arow) * K + (lane & 3) * 8;
    const short* Bg = Bw + (size_t)(n0 + brow) * K + (lane & 3) * 8;
    short* AsW = As + (wv * (BM / 4)) * 32;
    short* BsW = Bs + (wv * 32) * 32;

    const f32x4 z4 = {0.f, 0.f, 0.f, 0.f};
    f32x4 acc[RT][4];
#pragma unroll
    for (int r = 0; r < RT; ++r)
#pragma unroll
        for (int c = 0; c < 4; ++c) acc[r][c] = z4;

    const int lrow = lane & 15, kq = (lane >> 4) * 8;

    for (int kt = 0; kt < K; kt += 32) {
        __syncthreads();
        gl_lds16(Ag + kt, AsW);
        if constexpr (BM == 128) gl_lds16(Ag + (size_t)16 * K + kt, AsW + 16 * 32);
        gl_lds16(Bg + kt, BsW);
        gl_lds16(Bg + (size_t)16 * K + kt, BsW + 16 * 32);
        __syncthreads();
        short8 af[RT], bf[4];
#pragma unroll
        for (int r = 0; r < RT; ++r)
            af[r] = *(const short8*)&As[(wr + r * 16 + lrow) * 32 + kq];
#pragma unroll
        for (int c = 0; c < 4; ++c)
            bf[c] = *(const short8*)&Bs[(wc + c * 16 + lrow) * 32 + kq];
#pragma unroll
        for (int r = 0; r < RT; ++r)
#pragma unroll
            for (int c = 0; c < 4; ++c)
                acc[r][c] = __builtin_amdgcn_mfma_f32_16x16x32_bf16(af[r], bf[c], acc[r][c], 0, 0, 0);
    }

    const int col = lane & 15, rb = (lane >> 4) * 4;
#pragma unroll
    for (int c = 0; c < 4; ++c) {
        const int gn = n0 + wc + c * 16 + col;
        float bias;
        if constexpr (FUSED) {
            const int seg = gn >> 10;
            bias = (seg == 0 ? bb0 : seg == 1 ? bb1 : bb2)[gn & 1023];
        } else {
            bias = bb0[gn];
        }
#pragma unroll
        for (int r = 0; r < RT; ++r) {
            const int gm = m0 + wr + r * 16 + rb;
#pragma unroll
            for (int i = 0; i < 4; ++i) {
                float v = acc[r][c][i] + bias;
                if constexpr (ACT) v = gelu_erf(v);
                if constexpr (OUTBF)
                    ((short*)Cout)[(size_t)(gm + i) * N + gn] = f2bf(v);
                else
                    ((float*)Cout)[(size_t)(gm + i) * N + gn] = v;
            }
        }
    }
}

// ---------------------------------------------------------------------------
// MFMA flash attention v2.
//  - scores bounded in [-0.5, 0.13] (Poincare ball) -> NO online max: m=0,
//    l accumulated per-lane, reduced once at the end.
//  - computes S^T = K.Q^T so S's C-layout (col=qrow, row=key) IS the B-frag
//    layout for O^T = V^T.P^T -> no P LDS round-trip.
//  - K/V/Q staged from precomputed bf16 buffers: no conversions in hot loop.
// grid (L/128, H, B), block 256 (4 waves, 32 qrows/wave).
// ---------------------------------------------------------------------------
__global__ __launch_bounds__(256) void attn_mfma2(const short* __restrict__ Qb,
                                                  const short* __restrict__ Kb,
                                                  const short* __restrict__ Vtb,
                                                  const float* __restrict__ k2v,
                                                  short* __restrict__ aO) {
    const int qt = blockIdx.x, h = blockIdx.y, b = blockIdx.z;
    const int tid = threadIdx.x, wv = tid >> 6, lane = tid & 63;
    const int bh = b * NH + h;
    __shared__ __align__(16) short smem[2 * 64 * 72];   // Ks | Vt ; reused as Ot
    short* Ks = smem;
    short* Vt = smem + 64 * 72;
    const int lrow = lane & 15, q8 = (lane >> 4) * 8, q4 = (lane >> 4) * 4;

    const short* Qh = Qb + (size_t)bh * SEQ_L * HD;
    const short* Kh = Kb + (size_t)bh * SEQ_L * HD;
    const short* Vh = Vtb + (size_t)bh * HD * SEQ_L;
    const float* k2p = k2v + (size_t)bh * SEQ_L;

    // Q B-frags (B[n=qrow][k=hd]): loaded once
    short8 qf[2][2];
#pragma unroll
    for (int nt = 0; nt < 2; ++nt)
#pragma unroll
        for (int kc = 0; kc < 2; ++kc)
            qf[nt][kc] = *(const short8*)(Qh +
                (size_t)(qt * 128 + wv * 32 + nt * 16 + lrow) * HD + kc * 32 + q8);

    const f32x4 z4 = {0.f, 0.f, 0.f, 0.f};
    f32x4 o[4][2];   // O^T accum: [ht(hd)][nt(qrow)]
#pragma unroll
    for (int ht = 0; ht < 4; ++ht)
#pragma unroll
        for (int nt = 0; nt < 2; ++nt) o[ht][nt] = z4;
    float lsum[2] = {0.f, 0.f};

    const int srow = tid >> 2, sch = (tid & 3) * 16;

    for (int kt = 0; kt < SEQ_L / 64; ++kt) {
        const int k0 = kt * 64;
        __syncthreads();
        {   // stage K [key][hd] and V^T [hd][key], stride 72 (padded)
            const short* g = Kh + (size_t)(k0 + srow) * HD + sch;
            *(short8*)&Ks[srow * 72 + sch]     = *(const short8*)g;
            *(short8*)&Ks[srow * 72 + sch + 8] = *(const short8*)(g + 8);
            const short* gv = Vh + (size_t)srow * SEQ_L + k0 + sch;
            *(short8*)&Vt[srow * 72 + sch]     = *(const short8*)gv;
            *(short8*)&Vt[srow * 72 + sch + 8] = *(const short8*)(gv + 8);
        }
        __syncthreads();

        short8 p8[2][2];   // P^T B-frags [nt][c] being assembled (bf16)
#pragma unroll
        for (int mt = 0; mt < 4; ++mt) {
            const short8 kf0 = *(const short8*)&Ks[(mt * 16 + lrow) * 72 + q8];
            const short8 kf1 = *(const short8*)&Ks[(mt * 16 + lrow) * 72 + 32 + q8];
            const float4 kk = *(const float4*)(k2p + k0 + mt * 16 + q4);  // prescaled /8
            const int c = mt >> 1, hi = (mt & 1) * 4;
#pragma unroll
            for (int nt = 0; nt < 2; ++nt) {
                f32x4 s = z4;
                s = __builtin_amdgcn_mfma_f32_16x16x32_bf16(kf0, qf[nt][0], s, 0, 0, 0);
                s = __builtin_amdgcn_mfma_f32_16x16x32_bf16(kf1, qf[nt][1], s, 0, 0, 0);
#pragma unroll
                for (int i = 0; i < 4; ++i) {
                    const float kki = (i == 0) ? kk.x : (i == 1) ? kk.y : (i == 2) ? kk.z : kk.w;
                    const float p = __expf(fmaf(s[i], 0.25f, -kki));
                    lsum[nt] += p;
                    p8[nt][c][hi + i] = f2bf(p);
                }
            }
        }
        // PV: O^T += V^T . P^T  (V A-frags loaded in matching key order)
#pragma unroll
        for (int ht = 0; ht < 4; ++ht) {
#pragma unroll
            for (int c = 0; c < 2; ++c) {
                const s16x4 va = *(const s16x4*)&Vt[(ht * 16 + lrow) * 72 + c * 32 + q4];
                const s16x4 vb = *(const s16x4*)&Vt[(ht * 16 + lrow) * 72 + c * 32 + 16 + q4];
                const short8 v8 = {va[0], va[1], va[2], va[3], vb[0], vb[1], vb[2], vb[3]};
#pragma unroll
                for (int nt = 0; nt < 2; ++nt)
                    o[ht][nt] = __builtin_amdgcn_mfma_f32_16x16x32_bf16(v8, p8[nt][c], o[ht][nt], 0, 0, 0);
            }
        }
    }

    // final l reduction across the 4 quad groups (cols of same qrow)
#pragma unroll
    for (int nt = 0; nt < 2; ++nt) {
        lsum[nt] += __shfl_xor(lsum[nt], 16);
        lsum[nt] += __shfl_xor(lsum[nt], 32);
    }
    const float inv0 = 1.f / lsum[0], inv1 = 1.f / lsum[1];

    // epilogue: transpose O^T -> O via per-wave LDS (reuse smem)
    __syncthreads();
    short* Ot = smem + wv * (32 * 72);
#pragma unroll
    for (int ht = 0; ht < 4; ++ht)
#pragma unroll
        for (int nt = 0; nt < 2; ++nt) {
            const float iv = nt ? inv1 : inv0;
            const s16x4 ov = {f2bf(o[ht][nt][0] * iv), f2bf(o[ht][nt][1] * iv),
                              f2bf(o[ht][nt][2] * iv), f2bf(o[ht][nt][3] * iv)};
            *(s16x4*)&Ot[(nt * 16 + lrow) * 72 + ht * 16 + q4] = ov;
        }
    const int erow = lane >> 1, ec = (lane & 1) * 32;
    const short8 r0 = *(const short8*)&Ot[erow * 72 + ec + 0];
    const short8 r1 = *(const short8*)&Ot[erow * 72 + ec + 8];
    const short8 r2 = *(const short8*)&Ot[erow * 72 + ec + 16];
    const short8 r3 = *(const short8*)&Ot[erow * 72 + ec + 24];
    short* dst = aO + ((size_t)b * SEQ_L + qt * 128 + wv * 32 + erow) * DM + h * HD + ec;
    *(short8*)(dst + 0)  = r0;
    *(short8*)(dst + 8)  = r1;
    *(short8*)(dst + 16) = r2;
    *(short8*)(dst + 24) = r3;
}

// ---------------------------------------------------------------------------
// Launch
// ---------------------------------------------------------------------------
extern "C" void kernel_launch(void* const* d_in, const int* in_sizes, int n_in,
                              void* d_out, int out_size, void* d_ws, size_t ws_size,
                              hipStream_t stream) {
    const float* x   = (const float*)d_in[0];
    const float* wq  = (const float*)d_in[1];
    const float* bq  = (const float*)d_in[2];
    const float* wk  = (const float*)d_in[3];
    const float* bk  = (const float*)d_in[4];
    const float* wv  = (const float*)d_in[5];
    const float* bv  = (const float*)d_in[6];
    const float* wo  = (const float*)d_in[7];
    const float* bo  = (const float*)d_in[8];
    const float* g1  = (const float*)d_in[9];
    const float* b1  = (const float*)d_in[10];
    const float* g2  = (const float*)d_in[11];
    const float* b2  = (const float*)d_in[12];
    const float* w1  = (const float*)d_in[13];
    const float* bf1 = (const float*)d_in[14];
    const float* w2  = (const float*)d_in[15];
    const float* bf2 = (const float*)d_in[16];
    float* out = (float*)d_out;

    // ws layout (peak 80.25 MB):
    // [0,24)   wbf bf16 weights   [24,48) qkvB bf16 / P fp32 / hbuf(->56)
    // [48,56)  xnb -> Qb          [56,64) Kb  (later y2 low half)
    // [64,72)  Vtb -> xn2b (later y2 high half)
    // [72,72.25) k2               [72.25,80.25) aO
    char* base = (char*)d_ws;
    short* wbf  = (short*)base;
    short* qkvB = (short*)(base + (24u << 20));
    short* xnb  = (short*)(base + (48u << 20));
    short* Qb   = xnb;
    short* Kb   = (short*)(base + (56u << 20));
    short* Vtb  = (short*)(base + (64u << 20));
    float* k2   = (float*)(base + (72u << 20));
    short* aO   = (short*)(base + (72u << 20) + (256u << 10));
    float* P    = (float*)(base + (24u << 20));
    short* xn2b = Vtb;
    short* hbuf = qkvB;
    float* y2   = (float*)(base + (56u << 20));

    // 0. weights -> bf16
    cvt6_kernel<<<12288, 256, 0, stream>>>(wq, wk, wv, wo, w1, w2, wbf);
    // 1. LN1 -> bf16
    ln_bf16_kernel<<<BL, 256, 0, stream>>>(x, g1, b1, xnb);
    // 2. fused QKV projection -> bf16 [BL][3072]
    gemm_mfma<128, 0, 1, 1><<<dim3(24, 32), 256, 0, stream>>>(
        xnb, wbf, bq, bk, bv, qkvB, BL, QKV_S, DM);
    // 3. prep: project q,k -> Qb/Kb [bh][L][64] + k2; transpose v -> Vtb [bh][64][L]
    qk_prep<<<16384, 256, 0, stream>>>(qkvB, Qb, Kb, k2);
    v_prep<<<1024, 256, 0, stream>>>(qkvB, Vtb);
    // 4. flash MFMA attention -> aO bf16
    attn_mfma2<<<dim3(16, 16, 2), 256, 0, stream>>>(Qb, Kb, Vtb, k2, aO);
    // 5. output projection -> P fp32
    gemm_mfma<64, 0, 0, 0><<<dim3(8, 64), 256, 0, stream>>>(
        aO, wbf + 3145728, bo, bo, bo, P, BL, DM, DM);
    // 6. x1 = project(x + P) -> d_out
    resproj_kernel<<<BL, 256, 0, stream>>>(x, P, out);
    // 7. LN2 -> bf16
    ln_bf16_kernel<<<BL, 256, 0, stream>>>(out, g2, b2, xn2b);
    // 8. FFN1 + GELU -> bf16 hidden [24,56)
    gemm_mfma<128, 1, 1, 0><<<dim3(32, 32), 256, 0, stream>>>(
        xn2b, wbf + 4194304, bf1, bf1, bf1, hbuf, BL, DFF, DM);
    // 9. FFN2 -> fp32 y2 [56,72)
    gemm_mfma<64, 0, 0, 0><<<dim3(8, 64), 256, 0, stream>>>(
        hbuf, wbf + 8388608, bf2, bf2, bf2, y2, BL, DM, DFF);
    // 10. out = project(x1 + y2)
    resproj_kernel<<<BL, 256, 0, stream>>>(out, y2, out);
}

// Round 4
// 426.641 us; speedup vs baseline: 7.4518x; 1.0271x over previous
//
#include <hip/hip_runtime.h>
#include <math.h>

// Problem constants: B=2, L=2048, D=1024, H=16, hd=64, Dff=4096
#define SEQ_L 2048
#define DM    1024
#define NH    16
#define HD    64
#define BL    4096          // B*L
#define DFF   4096
#define QKV_S 3072          // fused qkv row stride

typedef __attribute__((ext_vector_type(8))) short short8;   // 8 bf16 (4 VGPRs)
typedef __attribute__((ext_vector_type(4))) short s16x4;    // 4 bf16
typedef __attribute__((ext_vector_type(4))) float f32x4;    // MFMA C/D frag

#define AS1 __attribute__((address_space(1)))
#define AS3 __attribute__((address_space(3)))

// async global->LDS, 16B per lane, lands at ldsbase + lane*16
__device__ __forceinline__ void gl_lds16(const void* g, void* l) {
    __builtin_amdgcn_global_load_lds((const AS1 void*)g, (AS3 void*)l, 16, 0, 0);
}

// fp32 -> bf16 round-to-nearest-even
__device__ __forceinline__ short f2bf(float x) {
    unsigned u = __float_as_uint(x);
    u += 0x7fff + ((u >> 16) & 1);
    return (short)(u >> 16);
}
__device__ __forceinline__ float bf2f(short s) {
    return __uint_as_float(((unsigned)(unsigned short)s) << 16);
}

// branch-free GELU (erf form) via A&S 7.1.26, |abs err| <= ~2e-7.
// gelu(x) = 0.5*(x + |x| * erf(|x|/sqrt2))
__device__ __forceinline__ float gelu_fast(float x) {
    const float xa = fabsf(x);
    const float z = xa * 0.70710678118654752440f;
    const float t = __builtin_amdgcn_rcpf(fmaf(0.3275911f, z, 1.f));
    float P = fmaf(t, 1.061405429f, -1.453152027f);
    P = fmaf(t, P, 1.421413741f);
    P = fmaf(t, P, -0.284496736f);
    P = fmaf(t, P, 0.254829592f);
    P *= t;
    const float e = __expf(-z * z);
    const float erfp = fmaf(-P, e, 1.f);   // erf(|x|/sqrt2)
    return 0.5f * fmaf(xa, erfp, x);
}

__device__ __forceinline__ float block_sum(float v, float* red, int tid) {
#pragma unroll
    for (int m = 32; m; m >>= 1) v += __shfl_xor(v, m);
    if ((tid & 63) == 0) red[tid >> 6] = v;
    __syncthreads();
    v = red[0] + red[1] + red[2] + red[3];
    __syncthreads();
    return v;
}

// ---------------------------------------------------------------------------
// Weight fp32 -> bf16: wq|wk|wv|wo|w1|w2 contiguous (fused QKV needs this).
// ---------------------------------------------------------------------------
__global__ __launch_bounds__(256) void cvt6_kernel(
    const float* __restrict__ wq, const float* __restrict__ wk,
    const float* __restrict__ wv, const float* __restrict__ wo,
    const float* __restrict__ w1, const float* __restrict__ w2,
    short* __restrict__ dst) {
    const size_t i = (size_t)blockIdx.x * 256 + threadIdx.x;  // float4 index
    const float* src;
    size_t off;
    if (i < 1048576) {
        const int seg = (int)(i >> 18);
        off = i & 262143;
        src = seg == 0 ? wq : seg == 1 ? wk : seg == 2 ? wv : wo;
    } else if (i < 2097152) { src = w1; off = i - 1048576; }
    else                    { src = w2; off = i - 2097152; }
    const float4 v = ((const float4*)src)[off];
    const s16x4 o = {f2bf(v.x), f2bf(v.y), f2bf(v.z), f2bf(v.w)};
    ((s16x4*)dst)[i] = o;
}

// ---------------------------------------------------------------------------
// LayerNorm over rows of 1024, bf16 output.
// ---------------------------------------------------------------------------
__global__ __launch_bounds__(256) void ln_bf16_kernel(const float* __restrict__ x,
                                                      const float* __restrict__ g,
                                                      const float* __restrict__ b,
                                                      short* __restrict__ out) {
    const int row = blockIdx.x;
    const int tid = threadIdx.x;
    __shared__ float red[4];
    const float4 xv = *(const float4*)(x + (size_t)row * DM + tid * 4);
    float s = xv.x + xv.y + xv.z + xv.w;
    s = block_sum(s, red, tid);
    const float mean = s * (1.f / (float)DM);
    float dx0 = xv.x - mean, dx1 = xv.y - mean, dx2 = xv.z - mean, dx3 = xv.w - mean;
    float ss = dx0 * dx0 + dx1 * dx1 + dx2 * dx2 + dx3 * dx3;
    ss = block_sum(ss, red, tid);
    const float rs = 1.f / sqrtf(ss * (1.f / (float)DM) + 1e-5f);
    const float4 gv = *(const float4*)(g + tid * 4);
    const float4 bv = *(const float4*)(b + tid * 4);
    const s16x4 ob = {f2bf(dx0 * rs * gv.x + bv.x), f2bf(dx1 * rs * gv.y + bv.y),
                      f2bf(dx2 * rs * gv.z + bv.z), f2bf(dx3 * rs * gv.w + bv.w)};
    *(s16x4*)(out + (size_t)row * DM + tid * 4) = ob;
}

// ---------------------------------------------------------------------------
// Residual + Poincare projection (fp32, in-place safe)
// ---------------------------------------------------------------------------
__global__ __launch_bounds__(256) void resproj_kernel(const float* __restrict__ a,
                                                      const float* __restrict__ c,
                                                      float* __restrict__ out) {
    const int row = blockIdx.x;
    const int tid = threadIdx.x;
    __shared__ float red[4];
    const float4 av = *(const float4*)(a + (size_t)row * DM + tid * 4);
    const float4 cv = *(const float4*)(c + (size_t)row * DM + tid * 4);
    float4 sv;
    sv.x = av.x + cv.x; sv.y = av.y + cv.y; sv.z = av.z + cv.z; sv.w = av.w + cv.w;
    float ss = sv.x * sv.x + sv.y * sv.y + sv.z * sv.z + sv.w * sv.w;
    ss = block_sum(ss, red, tid);
    const float n = sqrtf(ss);
    const float mx = 1.f - 1e-5f;
    const float scale = (n > mx) ? (mx / fmaxf(n, 1e-12f)) : 1.f;
    sv.x *= scale; sv.y *= scale; sv.z *= scale; sv.w *= scale;
    *(float4*)(out + (size_t)row * DM + tid * 4) = sv;
}

// ---------------------------------------------------------------------------
// q/k prep: per-head Poincare projection + attention-layout bf16 buffers.
// One wave per (row, head): Qb/Kb [b][h][L][64] bf16, k2 [b][h][L] = ||k||^2/8.
// ---------------------------------------------------------------------------
__global__ __launch_bounds__(256) void qk_prep(const short* __restrict__ qkvB,
                                               short* __restrict__ Qb,
                                               short* __restrict__ Kb,
                                               float* __restrict__ k2) {
    const int tid = threadIdx.x, lane = tid & 63;
    const int vec = blockIdx.x * 4 + (tid >> 6);
    const int row = vec >> 4, h = vec & 15;
    const int b = row >> 11, l = row & 2047;
    const size_t dstv = ((size_t)(b * NH + h) * SEQ_L + l) * HD + lane;
    const float mx = 1.f - 1e-5f;
    {   // q
        const float v = bf2f(qkvB[(size_t)row * QKV_S + h * HD + lane]);
        float s = v * v;
#pragma unroll
        for (int m = 32; m; m >>= 1) s += __shfl_xor(s, m);
        const float n = sqrtf(s);
        const float sc = (n > mx) ? (mx / fmaxf(n, 1e-12f)) : 1.f;
        Qb[dstv] = f2bf(v * sc);
    }
    {   // k (+ prescaled squared norm)
        const float v = bf2f(qkvB[(size_t)row * QKV_S + DM + h * HD + lane]);
        float s = v * v;
#pragma unroll
        for (int m = 32; m; m >>= 1) s += __shfl_xor(s, m);
        const float n = sqrtf(s);
        const float sc = (n > mx) ? (mx / fmaxf(n, 1e-12f)) : 1.f;
        Kb[dstv] = f2bf(v * sc);
        if (lane == 0) k2[(size_t)(b * NH + h) * SEQ_L + l] = s * sc * sc * 0.125f;
    }
}

// ---------------------------------------------------------------------------
// v prep: transpose to Vtb [b][h][64 hd][L] bf16 via LDS tile.
// ---------------------------------------------------------------------------
__global__ __launch_bounds__(256) void v_prep(const short* __restrict__ qkvB,
                                              short* __restrict__ Vtb) {
    const int blk = blockIdx.x;
    const int bh = blk >> 5, kt = blk & 31;
    const int b = bh >> 4, h = bh & 15;
    __shared__ short T[64 * 72];
    const int tid = threadIdx.x;
    {
        const int key = tid >> 2, ch = (tid & 3) * 16;
        const size_t src = ((size_t)b * SEQ_L + kt * 64 + key) * QKV_S + 2 * DM + h * HD + ch;
        *(short8*)&T[key * 72 + ch]     = *(const short8*)(qkvB + src);
        *(short8*)&T[key * 72 + ch + 8] = *(const short8*)(qkvB + src + 8);
    }
    __syncthreads();
    const int hd = tid >> 2, kc = (tid & 3) * 16;
    short8 o0, o1;
#pragma unroll
    for (int j = 0; j < 8; ++j) {
        o0[j] = T[(kc + j) * 72 + hd];
        o1[j] = T[(kc + 8 + j) * 72 + hd];
    }
    short* dst = Vtb + ((size_t)bh * HD + hd) * SEQ_L + kt * 64 + kc;
    *(short8*)dst = o0;
    *(short8*)(dst + 8) = o1;
}

// ---------------------------------------------------------------------------
// bf16 MFMA NT GEMM (m97 pattern): C[M,N] = A[M,K] @ B[N,K]^T + bias
// Block 256 (4 waves), tile BM x 128, BK=32, 16x16x32 bf16 MFMA.
// OUTBF&&BM==128: vectorized epilogue via per-wave LDS transpose
// (64 ds_write_b16 + 8 ds_read_b128 + 8 coalesced 16B stores per lane).
// ---------------------------------------------------------------------------
template <int BM, int ACT, int OUTBF, int FUSED>
__global__ __launch_bounds__(256) void gemm_mfma(
    const short* __restrict__ A, const short* __restrict__ Bw,
    const float* __restrict__ bb0, const float* __restrict__ bb1,
    const float* __restrict__ bb2, void* __restrict__ Cout,
    int M, int N, int K) {
    constexpr int RT = BM / 32;
    constexpr bool VEPI = (OUTBF != 0) && (BM == 128);
    constexpr int SMEM_BYTES = VEPI ? (4 * 64 * 72 * 2) : ((BM * 32 + 128 * 32) * 2);
    __shared__ __align__(16) char raw[SMEM_BYTES];
    short* As = (short*)raw;
    short* Bs = As + BM * 32;
    const int tid = threadIdx.x;
    const int wv = tid >> 6, lane = tid & 63;
    const int m0 = blockIdx.y * BM, n0 = blockIdx.x * 128;
    const int wr = (wv & 1) * (BM / 2);
    const int wc = (wv >> 1) * 64;

    const int arow = wv * (BM / 4) + (lane >> 2);
    const int brow = wv * 32 + (lane >> 2);
    const short* Ag = A + (size_t)(m0 + arow) * K + (lane & 3) * 8;
    const short* Bg = Bw + (size_t)(n0 + brow) * K + (lane & 3) * 8;
    short* AsW = As + (wv * (BM / 4)) * 32;
    short* BsW = Bs + (wv * 32) * 32;

    const f32x4 z4 = {0.f, 0.f, 0.f, 0.f};
    f32x4 acc[RT][4];
#pragma unroll
    for (int r = 0; r < RT; ++r)
#pragma unroll
        for (int c = 0; c < 4; ++c) acc[r][c] = z4;

    const int lrow = lane & 15, kq = (lane >> 4) * 8;

    for (int kt = 0; kt < K; kt += 32) {
        __syncthreads();
        gl_lds16(Ag + kt, AsW);
        if constexpr (BM == 128) gl_lds16(Ag + (size_t)16 * K + kt, AsW + 16 * 32);
        gl_lds16(Bg + kt, BsW);
        gl_lds16(Bg + (size_t)16 * K + kt, BsW + 16 * 32);
        __syncthreads();
        short8 af[RT], bf[4];
#pragma unroll
        for (int r = 0; r < RT; ++r)
            af[r] = *(const short8*)&As[(wr + r * 16 + lrow) * 32 + kq];
#pragma unroll
        for (int c = 0; c < 4; ++c)
            bf[c] = *(const short8*)&Bs[(wc + c * 16 + lrow) * 32 + kq];
#pragma unroll
        for (int r = 0; r < RT; ++r)
#pragma unroll
            for (int c = 0; c < 4; ++c)
                acc[r][c] = __builtin_amdgcn_mfma_f32_16x16x32_bf16(af[r], bf[c], acc[r][c], 0, 0, 0);
    }

    const int col = lane & 15, rb = (lane >> 4) * 4;
    if constexpr (VEPI) {
        __syncthreads();   // staging dead; reuse raw as per-wave transpose buffers
        short* Ot = (short*)raw + wv * (64 * 72);
#pragma unroll
        for (int c = 0; c < 4; ++c) {
            const int gn = n0 + wc + c * 16 + col;
            float bias;
            if constexpr (FUSED) {
                const int seg = gn >> 10;
                bias = (seg == 0 ? bb0 : seg == 1 ? bb1 : bb2)[gn & 1023];
            } else {
                bias = bb0[gn];
            }
#pragma unroll
            for (int r = 0; r < RT; ++r)
#pragma unroll
                for (int i = 0; i < 4; ++i) {
                    float v = acc[r][c][i] + bias;
                    if constexpr (ACT) v = gelu_fast(v);
                    Ot[(r * 16 + rb + i) * 72 + c * 16 + col] = f2bf(v);
                }
        }
        const int orow = lane >> 3, oc = (lane & 7) * 8;
#pragma unroll
        for (int it = 0; it < 8; ++it) {
            const short8 vv = *(const short8*)&Ot[(it * 8 + orow) * 72 + oc];
            *(short8*)((short*)Cout + (size_t)(m0 + wr + it * 8 + orow) * N + n0 + wc + oc) = vv;
        }
    } else {
#pragma unroll
        for (int c = 0; c < 4; ++c) {
            const int gn = n0 + wc + c * 16 + col;
            float bias;
            if constexpr (FUSED) {
                const int seg = gn >> 10;
                bias = (seg == 0 ? bb0 : seg == 1 ? bb1 : bb2)[gn & 1023];
            } else {
                bias = bb0[gn];
            }
#pragma unroll
            for (int r = 0; r < RT; ++r) {
                const int gm = m0 + wr + r * 16 + rb;
#pragma unroll
                for (int i = 0; i < 4; ++i) {
                    float v = acc[r][c][i] + bias;
                    if constexpr (ACT) v = gelu_fast(v);
                    if constexpr (OUTBF)
                        ((short*)Cout)[(size_t)(gm + i) * N + gn] = f2bf(v);
                    else
                        ((float*)Cout)[(size_t)(gm + i) * N + gn] = v;
                }
            }
        }
    }
}

// ---------------------------------------------------------------------------
// MFMA flash attention v2 (see R3 notes): S^T = K.Q^T, fixed max (scores
// bounded by Poincare ball), O^T = V^T.P^T, no P round-trip.
// ---------------------------------------------------------------------------
__global__ __launch_bounds__(256) void attn_mfma2(const short* __restrict__ Qb,
                                                  const short* __restrict__ Kb,
                                                  const short* __restrict__ Vtb,
                                                  const float* __restrict__ k2v,
                                                  short* __restrict__ aO) {
    const int qt = blockIdx.x, h = blockIdx.y, b = blockIdx.z;
    const int tid = threadIdx.x, wv = tid >> 6, lane = tid & 63;
    const int bh = b * NH + h;
    __shared__ __align__(16) short smem[2 * 64 * 72];   // Ks | Vt ; reused as Ot
    short* Ks = smem;
    short* Vt = smem + 64 * 72;
    const int lrow = lane & 15, q8 = (lane >> 4) * 8, q4 = (lane >> 4) * 4;

    const short* Qh = Qb + (size_t)bh * SEQ_L * HD;
    const short* Kh = Kb + (size_t)bh * SEQ_L * HD;
    const short* Vh = Vtb + (size_t)bh * HD * SEQ_L;
    const float* k2p = k2v + (size_t)bh * SEQ_L;

    short8 qf[2][2];
#pragma unroll
    for (int nt = 0; nt < 2; ++nt)
#pragma unroll
        for (int kc = 0; kc < 2; ++kc)
            qf[nt][kc] = *(const short8*)(Qh +
                (size_t)(qt * 128 + wv * 32 + nt * 16 + lrow) * HD + kc * 32 + q8);

    const f32x4 z4 = {0.f, 0.f, 0.f, 0.f};
    f32x4 o[4][2];   // O^T accum: [ht(hd)][nt(qrow)]
#pragma unroll
    for (int ht = 0; ht < 4; ++ht)
#pragma unroll
        for (int nt = 0; nt < 2; ++nt) o[ht][nt] = z4;
    float lsum[2] = {0.f, 0.f};

    const int srow = tid >> 2, sch = (tid & 3) * 16;

    for (int kt = 0; kt < SEQ_L / 64; ++kt) {
        const int k0 = kt * 64;
        __syncthreads();
        {
            const short* g = Kh + (size_t)(k0 + srow) * HD + sch;
            *(short8*)&Ks[srow * 72 + sch]     = *(const short8*)g;
            *(short8*)&Ks[srow * 72 + sch + 8] = *(const short8*)(g + 8);
            const short* gv = Vh + (size_t)srow * SEQ_L + k0 + sch;
            *(short8*)&Vt[srow * 72 + sch]     = *(const short8*)gv;
            *(short8*)&Vt[srow * 72 + sch + 8] = *(const short8*)(gv + 8);
        }
        __syncthreads();

        short8 p8[2][2];
#pragma unroll
        for (int mt = 0; mt < 4; ++mt) {
            const short8 kf0 = *(const short8*)&Ks[(mt * 16 + lrow) * 72 + q8];
            const short8 kf1 = *(const short8*)&Ks[(mt * 16 + lrow) * 72 + 32 + q8];
            const float4 kk = *(const float4*)(k2p + k0 + mt * 16 + q4);
            const int c = mt >> 1, hi = (mt & 1) * 4;
#pragma unroll
            for (int nt = 0; nt < 2; ++nt) {
                f32x4 s = z4;
                s = __builtin_amdgcn_mfma_f32_16x16x32_bf16(kf0, qf[nt][0], s, 0, 0, 0);
                s = __builtin_amdgcn_mfma_f32_16x16x32_bf16(kf1, qf[nt][1], s, 0, 0, 0);
#pragma unroll
                for (int i = 0; i < 4; ++i) {
                    const float kki = (i == 0) ? kk.x : (i == 1) ? kk.y : (i == 2) ? kk.z : kk.w;
                    const float p = __expf(fmaf(s[i], 0.25f, -kki));
                    lsum[nt] += p;
                    p8[nt][c][hi + i] = f2bf(p);
                }
            }
        }
#pragma unroll
        for (int ht = 0; ht < 4; ++ht) {
#pragma unroll
            for (int c = 0; c < 2; ++c) {
                const s16x4 va = *(const s16x4*)&Vt[(ht * 16 + lrow) * 72 + c * 32 + q4];
                const s16x4 vb = *(const s16x4*)&Vt[(ht * 16 + lrow) * 72 + c * 32 + 16 + q4];
                const short8 v8 = {va[0], va[1], va[2], va[3], vb[0], vb[1], vb[2], vb[3]};
#pragma unroll
                for (int nt = 0; nt < 2; ++nt)
                    o[ht][nt] = __builtin_amdgcn_mfma_f32_16x16x32_bf16(v8, p8[nt][c], o[ht][nt], 0, 0, 0);
            }
        }
    }

#pragma unroll
    for (int nt = 0; nt < 2; ++nt) {
        lsum[nt] += __shfl_xor(lsum[nt], 16);
        lsum[nt] += __shfl_xor(lsum[nt], 32);
    }
    const float inv0 = 1.f / lsum[0], inv1 = 1.f / lsum[1];

    __syncthreads();
    short* Ot = smem + wv * (32 * 72);
#pragma unroll
    for (int ht = 0; ht < 4; ++ht)
#pragma unroll
        for (int nt = 0; nt < 2; ++nt) {
            const float iv = nt ? inv1 : inv0;
            const s16x4 ov = {f2bf(o[ht][nt][0] * iv), f2bf(o[ht][nt][1] * iv),
                              f2bf(o[ht][nt][2] * iv), f2bf(o[ht][nt][3] * iv)};
            *(s16x4*)&Ot[(nt * 16 + lrow) * 72 + ht * 16 + q4] = ov;
        }
    const int erow = lane >> 1, ec = (lane & 1) * 32;
    const short8 r0 = *(const short8*)&Ot[erow * 72 + ec + 0];
    const short8 r1 = *(const short8*)&Ot[erow * 72 + ec + 8];
    const short8 r2 = *(const short8*)&Ot[erow * 72 + ec + 16];
    const short8 r3 = *(const short8*)&Ot[erow * 72 + ec + 24];
    short* dst = aO + ((size_t)b * SEQ_L + qt * 128 + wv * 32 + erow) * DM + h * HD + ec;
    *(short8*)(dst + 0)  = r0;
    *(short8*)(dst + 8)  = r1;
    *(short8*)(dst + 16) = r2;
    *(short8*)(dst + 24) = r3;
}

// ---------------------------------------------------------------------------
// Launch
// ---------------------------------------------------------------------------
extern "C" void kernel_launch(void* const* d_in, const int* in_sizes, int n_in,
                              void* d_out, int out_size, void* d_ws, size_t ws_size,
                              hipStream_t stream) {
    const float* x   = (const float*)d_in[0];
    const float* wq  = (const float*)d_in[1];
    const float* bq  = (const float*)d_in[2];
    const float* wk  = (const float*)d_in[3];
    const float* bk  = (const float*)d_in[4];
    const float* wv  = (const float*)d_in[5];
    const float* bv  = (const float*)d_in[6];
    const float* wo  = (const float*)d_in[7];
    const float* bo  = (const float*)d_in[8];
    const float* g1  = (const float*)d_in[9];
    const float* b1  = (const float*)d_in[10];
    const float* g2  = (const float*)d_in[11];
    const float* b2  = (const float*)d_in[12];
    const float* w1  = (const float*)d_in[13];
    const float* bf1 = (const float*)d_in[14];
    const float* w2  = (const float*)d_in[15];
    const float* bf2 = (const float*)d_in[16];
    float* out = (float*)d_out;

    char* base = (char*)d_ws;
    short* wbf  = (short*)base;
    short* qkvB = (short*)(base + (24u << 20));
    short* xnb  = (short*)(base + (48u << 20));
    short* Qb   = xnb;
    short* Kb   = (short*)(base + (56u << 20));
    short* Vtb  = (short*)(base + (64u << 20));
    float* k2   = (float*)(base + (72u << 20));
    short* aO   = (short*)(base + (72u << 20) + (256u << 10));
    float* P    = (float*)(base + (24u << 20));
    short* xn2b = Vtb;
    short* hbuf = qkvB;
    float* y2   = (float*)(base + (56u << 20));

    // 0. weights -> bf16
    cvt6_kernel<<<12288, 256, 0, stream>>>(wq, wk, wv, wo, w1, w2, wbf);
    // 1. LN1 -> bf16
    ln_bf16_kernel<<<BL, 256, 0, stream>>>(x, g1, b1, xnb);
    // 2. fused QKV projection -> bf16 [BL][3072]
    gemm_mfma<128, 0, 1, 1><<<dim3(24, 32), 256, 0, stream>>>(
        xnb, wbf, bq, bk, bv, qkvB, BL, QKV_S, DM);
    // 3. prep: project q,k -> Qb/Kb [bh][L][64] + k2; transpose v -> Vtb
    qk_prep<<<16384, 256, 0, stream>>>(qkvB, Qb, Kb, k2);
    v_prep<<<1024, 256, 0, stream>>>(qkvB, Vtb);
    // 4. flash MFMA attention -> aO bf16
    attn_mfma2<<<dim3(16, 16, 2), 256, 0, stream>>>(Qb, Kb, Vtb, k2, aO);
    // 5. output projection -> P fp32
    gemm_mfma<64, 0, 0, 0><<<dim3(8, 64), 256, 0, stream>>>(
        aO, wbf + 3145728, bo, bo, bo, P, BL, DM, DM);
    // 6. x1 = project(x + P) -> d_out
    resproj_kernel<<<BL, 256, 0, stream>>>(x, P, out);
    // 7. LN2 -> bf16
    ln_bf16_kernel<<<BL, 256, 0, stream>>>(out, g2, b2, xn2b);
    // 8. FFN1 + GELU -> bf16 hidden
    gemm_mfma<128, 1, 1, 0><<<dim3(32, 32), 256, 0, stream>>>(
        xn2b, wbf + 4194304, bf1, bf1, bf1, hbuf, BL, DFF, DM);
    // 9. FFN2 -> fp32 y2
    gemm_mfma<64, 0, 0, 0><<<dim3(8, 64), 256, 0, stream>>>(
        hbuf, wbf + 8388608, bf2, bf2, bf2, y2, BL, DM, DFF);
    // 10. out = project(x1 + y2)
    resproj_kernel<<<BL, 256, 0, stream>>>(out, y2, out);
}

// Round 5
// 399.093 us; speedup vs baseline: 7.9662x; 1.0690x over previous
//
#include <hip/hip_runtime.h>
#include <math.h>

// Problem constants: B=2, L=2048, D=1024, H=16, hd=64, Dff=4096
#define SEQ_L 2048
#define DM    1024
#define NH    16
#define HD    64
#define BL    4096          // B*L
#define DFF   4096
#define QKV_S 3072          // fused qkv row stride

typedef __attribute__((ext_vector_type(8))) short short8;   // 8 bf16 (4 VGPRs)
typedef __attribute__((ext_vector_type(4))) short s16x4;    // 4 bf16
typedef __attribute__((ext_vector_type(4))) float f32x4;    // MFMA C/D frag

// fp32 -> bf16 round-to-nearest-even
__device__ __forceinline__ short f2bf(float x) {
    unsigned u = __float_as_uint(x);
    u += 0x7fff + ((u >> 16) & 1);
    return (short)(u >> 16);
}
__device__ __forceinline__ float bf2f(short s) {
    return __uint_as_float(((unsigned)(unsigned short)s) << 16);
}

// branch-free GELU (erf form) via A&S 7.1.26, |abs err| <= ~2e-7.
__device__ __forceinline__ float gelu_fast(float x) {
    const float xa = fabsf(x);
    const float z = xa * 0.70710678118654752440f;
    const float t = __builtin_amdgcn_rcpf(fmaf(0.3275911f, z, 1.f));
    float P = fmaf(t, 1.061405429f, -1.453152027f);
    P = fmaf(t, P, 1.421413741f);
    P = fmaf(t, P, -0.284496736f);
    P = fmaf(t, P, 0.254829592f);
    P *= t;
    const float e = __expf(-z * z);
    const float erfp = fmaf(-P, e, 1.f);   // erf(|x|/sqrt2)
    return 0.5f * fmaf(xa, erfp, x);
}

__device__ __forceinline__ float block_sum(float v, float* red, int tid) {
#pragma unroll
    for (int m = 32; m; m >>= 1) v += __shfl_xor(v, m);
    if ((tid & 63) == 0) red[tid >> 6] = v;
    __syncthreads();
    v = red[0] + red[1] + red[2] + red[3];
    __syncthreads();
    return v;
}

// ---------------------------------------------------------------------------
// Weight fp32 -> bf16: wq|wk|wv|wo|w1|w2 contiguous (fused QKV needs this).
// ---------------------------------------------------------------------------
__global__ __launch_bounds__(256) void cvt6_kernel(
    const float* __restrict__ wq, const float* __restrict__ wk,
    const float* __restrict__ wv, const float* __restrict__ wo,
    const float* __restrict__ w1, const float* __restrict__ w2,
    short* __restrict__ dst) {
    const size_t i = (size_t)blockIdx.x * 256 + threadIdx.x;  // float4 index
    const float* src;
    size_t off;
    if (i < 1048576) {
        const int seg = (int)(i >> 18);
        off = i & 262143;
        src = seg == 0 ? wq : seg == 1 ? wk : seg == 2 ? wv : wo;
    } else if (i < 2097152) { src = w1; off = i - 1048576; }
    else                    { src = w2; off = i - 2097152; }
    const float4 v = ((const float4*)src)[off];
    const s16x4 o = {f2bf(v.x), f2bf(v.y), f2bf(v.z), f2bf(v.w)};
    ((s16x4*)dst)[i] = o;
}

// ---------------------------------------------------------------------------
// LayerNorm over rows of 1024, bf16 output.
// ---------------------------------------------------------------------------
__global__ __launch_bounds__(256) void ln_bf16_kernel(const float* __restrict__ x,
                                                      const float* __restrict__ g,
                                                      const float* __restrict__ b,
                                                      short* __restrict__ out) {
    const int row = blockIdx.x;
    const int tid = threadIdx.x;
    __shared__ float red[4];
    const float4 xv = *(const float4*)(x + (size_t)row * DM + tid * 4);
    float s = xv.x + xv.y + xv.z + xv.w;
    s = block_sum(s, red, tid);
    const float mean = s * (1.f / (float)DM);
    float dx0 = xv.x - mean, dx1 = xv.y - mean, dx2 = xv.z - mean, dx3 = xv.w - mean;
    float ss = dx0 * dx0 + dx1 * dx1 + dx2 * dx2 + dx3 * dx3;
    ss = block_sum(ss, red, tid);
    const float rs = 1.f / sqrtf(ss * (1.f / (float)DM) + 1e-5f);
    const float4 gv = *(const float4*)(g + tid * 4);
    const float4 bv = *(const float4*)(b + tid * 4);
    const s16x4 ob = {f2bf(dx0 * rs * gv.x + bv.x), f2bf(dx1 * rs * gv.y + bv.y),
                      f2bf(dx2 * rs * gv.z + bv.z), f2bf(dx3 * rs * gv.w + bv.w)};
    *(s16x4*)(out + (size_t)row * DM + tid * 4) = ob;
}

// ---------------------------------------------------------------------------
// Residual + Poincare projection (fp32, in-place safe)
// ---------------------------------------------------------------------------
__global__ __launch_bounds__(256) void resproj_kernel(const float* __restrict__ a,
                                                      const float* __restrict__ c,
                                                      float* __restrict__ out) {
    const int row = blockIdx.x;
    const int tid = threadIdx.x;
    __shared__ float red[4];
    const float4 av = *(const float4*)(a + (size_t)row * DM + tid * 4);
    const float4 cv = *(const float4*)(c + (size_t)row * DM + tid * 4);
    float4 sv;
    sv.x = av.x + cv.x; sv.y = av.y + cv.y; sv.z = av.z + cv.z; sv.w = av.w + cv.w;
    float ss = sv.x * sv.x + sv.y * sv.y + sv.z * sv.z + sv.w * sv.w;
    ss = block_sum(ss, red, tid);
    const float n = sqrtf(ss);
    const float mx = 1.f - 1e-5f;
    const float scale = (n > mx) ? (mx / fmaxf(n, 1e-12f)) : 1.f;
    sv.x *= scale; sv.y *= scale; sv.z *= scale; sv.w *= scale;
    *(float4*)(out + (size_t)row * DM + tid * 4) = sv;
}

// ---------------------------------------------------------------------------
// q/k prep: per-head Poincare projection + attention-layout bf16 buffers.
// ---------------------------------------------------------------------------
__global__ __launch_bounds__(256) void qk_prep(const short* __restrict__ qkvB,
                                               short* __restrict__ Qb,
                                               short* __restrict__ Kb,
                                               float* __restrict__ k2) {
    const int tid = threadIdx.x, lane = tid & 63;
    const int vec = blockIdx.x * 4 + (tid >> 6);
    const int row = vec >> 4, h = vec & 15;
    const int b = row >> 11, l = row & 2047;
    const size_t dstv = ((size_t)(b * NH + h) * SEQ_L + l) * HD + lane;
    const float mx = 1.f - 1e-5f;
    {   // q
        const float v = bf2f(qkvB[(size_t)row * QKV_S + h * HD + lane]);
        float s = v * v;
#pragma unroll
        for (int m = 32; m; m >>= 1) s += __shfl_xor(s, m);
        const float n = sqrtf(s);
        const float sc = (n > mx) ? (mx / fmaxf(n, 1e-12f)) : 1.f;
        Qb[dstv] = f2bf(v * sc);
    }
    {   // k (+ prescaled squared norm)
        const float v = bf2f(qkvB[(size_t)row * QKV_S + DM + h * HD + lane]);
        float s = v * v;
#pragma unroll
        for (int m = 32; m; m >>= 1) s += __shfl_xor(s, m);
        const float n = sqrtf(s);
        const float sc = (n > mx) ? (mx / fmaxf(n, 1e-12f)) : 1.f;
        Kb[dstv] = f2bf(v * sc);
        if (lane == 0) k2[(size_t)(b * NH + h) * SEQ_L + l] = s * sc * sc * 0.125f;
    }
}

// ---------------------------------------------------------------------------
// v prep: transpose to Vtb [b][h][64 hd][L] bf16 via LDS tile.
// ---------------------------------------------------------------------------
__global__ __launch_bounds__(256) void v_prep(const short* __restrict__ qkvB,
                                              short* __restrict__ Vtb) {
    const int blk = blockIdx.x;
    const int bh = blk >> 5, kt = blk & 31;
    const int b = bh >> 4, h = bh & 15;
    __shared__ short T[64 * 72];
    const int tid = threadIdx.x;
    {
        const int key = tid >> 2, ch = (tid & 3) * 16;
        const size_t src = ((size_t)b * SEQ_L + kt * 64 + key) * QKV_S + 2 * DM + h * HD + ch;
        *(short8*)&T[key * 72 + ch]     = *(const short8*)(qkvB + src);
        *(short8*)&T[key * 72 + ch + 8] = *(const short8*)(qkvB + src + 8);
    }
    __syncthreads();
    const int hd = tid >> 2, kc = (tid & 3) * 16;
    short8 o0, o1;
#pragma unroll
    for (int j = 0; j < 8; ++j) {
        o0[j] = T[(kc + j) * 72 + hd];
        o1[j] = T[(kc + 8 + j) * 72 + hd];
    }
    short* dst = Vtb + ((size_t)bh * HD + hd) * SEQ_L + kt * 64 + kc;
    *(short8*)dst = o0;
    *(short8*)(dst + 8) = o1;
}

// ---------------------------------------------------------------------------
// bf16 MFMA NT GEMM with REGISTER-PREFETCH DOUBLE BUFFER:
// tile k+1 is loaded into VGPRs while tile k is MFMA'd from LDS; plain
// global_load results are NOT drained by __syncthreads (unlike
// global_load_lds), so the vmcnt wait lands before next iter's ds_write —
// a full compute-phase after issue. Chosen for low-occupancy grids
// (512 blocks = 2/CU) where wave-level TLP can't hide HBM latency.
// ---------------------------------------------------------------------------
template <int BM, int ACT, int OUTBF, int FUSED>
__global__ __launch_bounds__(256) void gemm_mfma(
    const short* __restrict__ A, const short* __restrict__ Bw,
    const float* __restrict__ bb0, const float* __restrict__ bb1,
    const float* __restrict__ bb2, void* __restrict__ Cout,
    int M, int N, int K) {
    constexpr int RT = BM / 32;
    constexpr bool VEPI = (OUTBF != 0) && (BM == 128);
    constexpr int SMEM_BYTES = VEPI ? (4 * 64 * 72 * 2) : ((BM * 32 + 128 * 32) * 2);
    __shared__ __align__(16) char raw[SMEM_BYTES];
    short* As = (short*)raw;
    short* Bs = As + BM * 32;
    const int tid = threadIdx.x;
    const int wv = tid >> 6, lane = tid & 63;
    const int m0 = blockIdx.y * BM, n0 = blockIdx.x * 128;
    const int wr = (wv & 1) * (BM / 2);
    const int wc = (wv >> 1) * 64;

    const int arow = wv * (BM / 4) + (lane >> 2);
    const int brow = wv * 32 + (lane >> 2);
    const short* Ag = A + (size_t)(m0 + arow) * K + (lane & 3) * 8;
    const short* Bg = Bw + (size_t)(n0 + brow) * K + (lane & 3) * 8;
    // LDS staging dests (layout [row][32]; lane writes 16B at base+lane*16)
    short* AsW = As + (wv * (BM / 4)) * 32 + lane * 8;
    short* AsW2 = AsW + 16 * 32;
    short* BsW = Bs + (wv * 32) * 32 + lane * 8;
    short* BsW2 = BsW + 16 * 32;

    const f32x4 z4 = {0.f, 0.f, 0.f, 0.f};
    f32x4 acc[RT][4];
#pragma unroll
    for (int r = 0; r < RT; ++r)
#pragma unroll
        for (int c = 0; c < 4; ++c) acc[r][c] = z4;

    const int lrow = lane & 15, kq = (lane >> 4) * 8;

    // prologue: tile 0 into regs
    short8 ra0, ra1, rb0, rb1;
    ra0 = *(const short8*)(Ag);
    if constexpr (BM == 128) ra1 = *(const short8*)(Ag + (size_t)16 * K);
    rb0 = *(const short8*)(Bg);
    rb1 = *(const short8*)(Bg + (size_t)16 * K);

    for (int kt = 0; kt < K; kt += 32) {
        __syncthreads();                    // previous tile's ds_reads complete
        *(short8*)AsW = ra0;                // vmcnt wait (issued last iter) here
        if constexpr (BM == 128) *(short8*)AsW2 = ra1;
        *(short8*)BsW = rb0;
        *(short8*)BsW2 = rb1;
        short8 na0, na1, nb0, nb1;
        if (kt + 32 < K) {                  // prefetch tile k+1 (in flight
            na0 = *(const short8*)(Ag + kt + 32);          //  through MFMAs)
            if constexpr (BM == 128) na1 = *(const short8*)(Ag + (size_t)16 * K + kt + 32);
            nb0 = *(const short8*)(Bg + kt + 32);
            nb1 = *(const short8*)(Bg + (size_t)16 * K + kt + 32);
        }
        __syncthreads();                    // LDS writes visible
        short8 af[RT], bf[4];
#pragma unroll
        for (int r = 0; r < RT; ++r)
            af[r] = *(const short8*)&As[(wr + r * 16 + lrow) * 32 + kq];
#pragma unroll
        for (int c = 0; c < 4; ++c)
            bf[c] = *(const short8*)&Bs[(wc + c * 16 + lrow) * 32 + kq];
#pragma unroll
        for (int r = 0; r < RT; ++r)
#pragma unroll
            for (int c = 0; c < 4; ++c)
                acc[r][c] = __builtin_amdgcn_mfma_f32_16x16x32_bf16(af[r], bf[c], acc[r][c], 0, 0, 0);
        ra0 = na0; ra1 = na1; rb0 = nb0; rb1 = nb1;
    }

    const int col = lane & 15, rb = (lane >> 4) * 4;
    if constexpr (VEPI) {
        __syncthreads();   // staging dead; reuse raw as per-wave transpose buffers
        short* Ot = (short*)raw + wv * (64 * 72);
#pragma unroll
        for (int c = 0; c < 4; ++c) {
            const int gn = n0 + wc + c * 16 + col;
            float bias;
            if constexpr (FUSED) {
                const int seg = gn >> 10;
                bias = (seg == 0 ? bb0 : seg == 1 ? bb1 : bb2)[gn & 1023];
            } else {
                bias = bb0[gn];
            }
#pragma unroll
            for (int r = 0; r < RT; ++r)
#pragma unroll
                for (int i = 0; i < 4; ++i) {
                    float v = acc[r][c][i] + bias;
                    if constexpr (ACT) v = gelu_fast(v);
                    Ot[(r * 16 + rb + i) * 72 + c * 16 + col] = f2bf(v);
                }
        }
        const int orow = lane >> 3, oc = (lane & 7) * 8;
#pragma unroll
        for (int it = 0; it < 8; ++it) {
            const short8 vv = *(const short8*)&Ot[(it * 8 + orow) * 72 + oc];
            *(short8*)((short*)Cout + (size_t)(m0 + wr + it * 8 + orow) * N + n0 + wc + oc) = vv;
        }
    } else {
#pragma unroll
        for (int c = 0; c < 4; ++c) {
            const int gn = n0 + wc + c * 16 + col;
            float bias;
            if constexpr (FUSED) {
                const int seg = gn >> 10;
                bias = (seg == 0 ? bb0 : seg == 1 ? bb1 : bb2)[gn & 1023];
            } else {
                bias = bb0[gn];
            }
#pragma unroll
            for (int r = 0; r < RT; ++r) {
                const int gm = m0 + wr + r * 16 + rb;
#pragma unroll
                for (int i = 0; i < 4; ++i) {
                    float v = acc[r][c][i] + bias;
                    if constexpr (ACT) v = gelu_fast(v);
                    if constexpr (OUTBF)
                        ((short*)Cout)[(size_t)(gm + i) * N + gn] = f2bf(v);
                    else
                        ((float*)Cout)[(size_t)(gm + i) * N + gn] = v;
                }
            }
        }
    }
}

// ---------------------------------------------------------------------------
// MFMA flash attention v2: S^T = K.Q^T, fixed max (scores bounded by the
// Poincare ball), O^T = V^T.P^T, no P round-trip.
// ---------------------------------------------------------------------------
__global__ __launch_bounds__(256) void attn_mfma2(const short* __restrict__ Qb,
                                                  const short* __restrict__ Kb,
                                                  const short* __restrict__ Vtb,
                                                  const float* __restrict__ k2v,
                                                  short* __restrict__ aO) {
    const int qt = blockIdx.x, h = blockIdx.y, b = blockIdx.z;
    const int tid = threadIdx.x, wv = tid >> 6, lane = tid & 63;
    const int bh = b * NH + h;
    __shared__ __align__(16) short smem[2 * 64 * 72];   // Ks | Vt ; reused as Ot
    short* Ks = smem;
    short* Vt = smem + 64 * 72;
    const int lrow = lane & 15, q8 = (lane >> 4) * 8, q4 = (lane >> 4) * 4;

    const short* Qh = Qb + (size_t)bh * SEQ_L * HD;
    const short* Kh = Kb + (size_t)bh * SEQ_L * HD;
    const short* Vh = Vtb + (size_t)bh * HD * SEQ_L;
    const float* k2p = k2v + (size_t)bh * SEQ_L;

    short8 qf[2][2];
#pragma unroll
    for (int nt = 0; nt < 2; ++nt)
#pragma unroll
        for (int kc = 0; kc < 2; ++kc)
            qf[nt][kc] = *(const short8*)(Qh +
                (size_t)(qt * 128 + wv * 32 + nt * 16 + lrow) * HD + kc * 32 + q8);

    const f32x4 z4 = {0.f, 0.f, 0.f, 0.f};
    f32x4 o[4][2];   // O^T accum: [ht(hd)][nt(qrow)]
#pragma unroll
    for (int ht = 0; ht < 4; ++ht)
#pragma unroll
        for (int nt = 0; nt < 2; ++nt) o[ht][nt] = z4;
    float lsum[2] = {0.f, 0.f};

    const int srow = tid >> 2, sch = (tid & 3) * 16;

    for (int kt = 0; kt < SEQ_L / 64; ++kt) {
        const int k0 = kt * 64;
        __syncthreads();
        {
            const short* g = Kh + (size_t)(k0 + srow) * HD + sch;
            *(short8*)&Ks[srow * 72 + sch]     = *(const short8*)g;
            *(short8*)&Ks[srow * 72 + sch + 8] = *(const short8*)(g + 8);
            const short* gv = Vh + (size_t)srow * SEQ_L + k0 + sch;
            *(short8*)&Vt[srow * 72 + sch]     = *(const short8*)gv;
            *(short8*)&Vt[srow * 72 + sch + 8] = *(const short8*)(gv + 8);
        }
        __syncthreads();

        short8 p8[2][2];
#pragma unroll
        for (int mt = 0; mt < 4; ++mt) {
            const short8 kf0 = *(const short8*)&Ks[(mt * 16 + lrow) * 72 + q8];
            const short8 kf1 = *(const short8*)&Ks[(mt * 16 + lrow) * 72 + 32 + q8];
            const float4 kk = *(const float4*)(k2p + k0 + mt * 16 + q4);
            const int c = mt >> 1, hi = (mt & 1) * 4;
#pragma unroll
            for (int nt = 0; nt < 2; ++nt) {
                f32x4 s = z4;
                s = __builtin_amdgcn_mfma_f32_16x16x32_bf16(kf0, qf[nt][0], s, 0, 0, 0);
                s = __builtin_amdgcn_mfma_f32_16x16x32_bf16(kf1, qf[nt][1], s, 0, 0, 0);
#pragma unroll
                for (int i = 0; i < 4; ++i) {
                    const float kki = (i == 0) ? kk.x : (i == 1) ? kk.y : (i == 2) ? kk.z : kk.w;
                    const float p = __expf(fmaf(s[i], 0.25f, -kki));
                    lsum[nt] += p;
                    p8[nt][c][hi + i] = f2bf(p);
                }
            }
        }
#pragma unroll
        for (int ht = 0; ht < 4; ++ht) {
#pragma unroll
            for (int c = 0; c < 2; ++c) {
                const s16x4 va = *(const s16x4*)&Vt[(ht * 16 + lrow) * 72 + c * 32 + q4];
                const s16x4 vb = *(const s16x4*)&Vt[(ht * 16 + lrow) * 72 + c * 32 + 16 + q4];
                const short8 v8 = {va[0], va[1], va[2], va[3], vb[0], vb[1], vb[2], vb[3]};
#pragma unroll
                for (int nt = 0; nt < 2; ++nt)
                    o[ht][nt] = __builtin_amdgcn_mfma_f32_16x16x32_bf16(v8, p8[nt][c], o[ht][nt], 0, 0, 0);
            }
        }
    }

#pragma unroll
    for (int nt = 0; nt < 2; ++nt) {
        lsum[nt] += __shfl_xor(lsum[nt], 16);
        lsum[nt] += __shfl_xor(lsum[nt], 32);
    }
    const float inv0 = 1.f / lsum[0], inv1 = 1.f / lsum[1];

    __syncthreads();
    short* Ot = smem + wv * (32 * 72);
#pragma unroll
    for (int ht = 0; ht < 4; ++ht)
#pragma unroll
        for (int nt = 0; nt < 2; ++nt) {
            const float iv = nt ? inv1 : inv0;
            const s16x4 ov = {f2bf(o[ht][nt][0] * iv), f2bf(o[ht][nt][1] * iv),
                              f2bf(o[ht][nt][2] * iv), f2bf(o[ht][nt][3] * iv)};
            *(s16x4*)&Ot[(nt * 16 + lrow) * 72 + ht * 16 + q4] = ov;
        }
    const int erow = lane >> 1, ec = (lane & 1) * 32;
    const short8 r0 = *(const short8*)&Ot[erow * 72 + ec + 0];
    const short8 r1 = *(const short8*)&Ot[erow * 72 + ec + 8];
    const short8 r2 = *(const short8*)&Ot[erow * 72 + ec + 16];
    const short8 r3 = *(const short8*)&Ot[erow * 72 + ec + 24];
    short* dst = aO + ((size_t)b * SEQ_L + qt * 128 + wv * 32 + erow) * DM + h * HD + ec;
    *(short8*)(dst + 0)  = r0;
    *(short8*)(dst + 8)  = r1;
    *(short8*)(dst + 16) = r2;
    *(short8*)(dst + 24) = r3;
}

// ---------------------------------------------------------------------------
// Launch
// ---------------------------------------------------------------------------
extern "C" void kernel_launch(void* const* d_in, const int* in_sizes, int n_in,
                              void* d_out, int out_size, void* d_ws, size_t ws_size,
                              hipStream_t stream) {
    const float* x   = (const float*)d_in[0];
    const float* wq  = (const float*)d_in[1];
    const float* bq  = (const float*)d_in[2];
    const float* wk  = (const float*)d_in[3];
    const float* bk  = (const float*)d_in[4];
    const float* wv  = (const float*)d_in[5];
    const float* bv  = (const float*)d_in[6];
    const float* wo  = (const float*)d_in[7];
    const float* bo  = (const float*)d_in[8];
    const float* g1  = (const float*)d_in[9];
    const float* b1  = (const float*)d_in[10];
    const float* g2  = (const float*)d_in[11];
    const float* b2  = (const float*)d_in[12];
    const float* w1  = (const float*)d_in[13];
    const float* bf1 = (const float*)d_in[14];
    const float* w2  = (const float*)d_in[15];
    const float* bf2 = (const float*)d_in[16];
    float* out = (float*)d_out;

    // ws layout (bytes):
    // [0,24)    wbf bf16 weights
    // [24,57.6) qkvB bf16 [BL][3072] -> P fp32 -> hbuf bf16 [BL][4096]
    // [48,56)   xnb/Qb (inside [24..) after qkvB dead? NO — xnb/Qb at [48,56)
    //           only alive before/through QKV + attn; P fp32 [24,40.8) is fine.
    // [56,64)   Kb          [64,72) Vtb / xn2b
    // [72,72.25) k2         [72.25,80.25) aO
    // [58,74.8) y2 fp32 (written step 9, after hbuf/Kb/Vtb/aO all dead)
    char* base = (char*)d_ws;
    short* wbf  = (short*)base;
    short* qkvB = (short*)(base + (24u << 20));
    short* xnb  = (short*)(base + (48u << 20));
    short* Qb   = xnb;
    short* Kb   = (short*)(base + (56u << 20));
    short* Vtb  = (short*)(base + (64u << 20));
    float* k2   = (float*)(base + (72u << 20));
    short* aO   = (short*)(base + (72u << 20) + (256u << 10));
    float* P    = (float*)(base + (24u << 20));
    short* xn2b = Vtb;
    short* hbuf = qkvB;
    float* y2   = (float*)(base + (58u << 20));   // no overlap with hbuf [24,57.6)

    // 0. weights -> bf16
    cvt6_kernel<<<12288, 256, 0, stream>>>(wq, wk, wv, wo, w1, w2, wbf);
    // 1. LN1 -> bf16
    ln_bf16_kernel<<<BL, 256, 0, stream>>>(x, g1, b1, xnb);
    // 2. fused QKV projection -> bf16 [BL][3072]
    gemm_mfma<128, 0, 1, 1><<<dim3(24, 32), 256, 0, stream>>>(
        xnb, wbf, bq, bk, bv, qkvB, BL, QKV_S, DM);
    // 3. prep: project q,k -> Qb/Kb [bh][L][64] + k2; transpose v -> Vtb
    qk_prep<<<16384, 256, 0, stream>>>(qkvB, Qb, Kb, k2);
    v_prep<<<1024, 256, 0, stream>>>(qkvB, Vtb);
    // 4. flash MFMA attention -> aO bf16
    attn_mfma2<<<dim3(16, 16, 2), 256, 0, stream>>>(Qb, Kb, Vtb, k2, aO);
    // 5. output projection -> P fp32
    gemm_mfma<64, 0, 0, 0><<<dim3(8, 64), 256, 0, stream>>>(
        aO, wbf + 3145728, bo, bo, bo, P, BL, DM, DM);
    // 6. x1 = project(x + P) -> d_out
    resproj_kernel<<<BL, 256, 0, stream>>>(x, P, out);
    // 7. LN2 -> bf16
    ln_bf16_kernel<<<BL, 256, 0, stream>>>(out, g2, b2, xn2b);
    // 8. FFN1 + GELU -> bf16 hidden
    gemm_mfma<128, 1, 1, 0><<<dim3(32, 32), 256, 0, stream>>>(
        xn2b, wbf + 4194304, bf1, bf1, bf1, hbuf, BL, DFF, DM);
    // 9. FFN2 -> fp32 y2
    gemm_mfma<64, 0, 0, 0><<<dim3(8, 64), 256, 0, stream>>>(
        hbuf, wbf + 8388608, bf2, bf2, bf2, y2, BL, DM, DFF);
    // 10. out = project(x1 + y2)
    resproj_kernel<<<BL, 256, 0, stream>>>(out, y2, out);
}